// Round 6
// baseline (109.112 us; speedup 1.0000x reference)
//
#include <hip/hip_runtime.h>
#include <hip/hip_bf16.h>

// B=8, N=64, P=128, DNODE=2048, DEDGE=1024, DEMB=512, E=32768
// edge_locating_tensor is the canonical meshgrid -> lookup(b,i,j)=b*4096+i*64+j.
// Only 2*B*P=2048 of 32768 edge rows used; (e1+e2)*0.5 folds into the GEMM input.
// Structure: k_prep (high-TLP, 5126 blocks) -> k_main (320 blocks: both GEMMs,
// grid barrier, scores+first-half). R5 bug fixed: edge blocks 192..319 now take
// ONE tile each (e = bid-192, 128 tiles total) — R5 generated 256 tiles -> OOB.

typedef _Float16 h16;
typedef h16 h16x4 __attribute__((ext_vector_type(4)));
typedef h16 h16x8 __attribute__((ext_vector_type(8)));
typedef float f32x4 __attribute__((ext_vector_type(4)));

// ---------------- ws layout (bytes) ----------------
static const long O_XH   = 0;         // 512*2048*2
static const long O_W3T  = 2097152;   // 1536*2048*2
static const long O_WREL = 8388608;   // 512*1024*2
static const long O_G    = 9437184;   // 1024*1024*2
static const long O_B3   = 11534336;  // 1536*4
static const long O_Y    = 11540480;  // 512*1536*4
static const long O_YH   = 14686208;  // 512*1024*2
static const long O_CNT  = 15734784;  // 4 (memset to 0 every call)

__global__ __launch_bounds__(256) void k_prep(
    const float* __restrict__ Wphi, const float* __restrict__ Wpsi,
    const float* __restrict__ Wnode, const float* __restrict__ Wrel,
    const float* __restrict__ x, const float* __restrict__ bphi,
    const float* __restrict__ bpsi, const float* __restrict__ bnode,
    const float* __restrict__ feat, const int* __restrict__ pairs,
    h16* __restrict__ W3t, h16* __restrict__ Wrelt, h16* __restrict__ xh,
    float* __restrict__ b3, h16* __restrict__ G) {
  __shared__ float t[32][33];
  int bid = blockIdx.x, tid = threadIdx.x;
  if (bid < 3584) {
    // weight transpose+cvt, 32x32 f32 tile: float4 loads, h16x4 stores
    const float* src; h16* dst; int K, tk, tn;
    if (bid < 3072) {
      int mat = bid >> 10, rem = bid & 1023;
      tk = rem >> 4; tn = rem & 15;
      src = mat == 0 ? Wphi : (mat == 1 ? Wpsi : Wnode);
      K = 2048; dst = W3t + (long)mat * 512 * 2048;
    } else {
      int rem = bid - 3072;
      tk = rem >> 4; tn = rem & 15;
      src = Wrel; K = 1024; dst = Wrelt;
    }
    {
      int row = tid >> 3, c4 = (tid & 7) * 4;   // 32 rows x 8 float4
      float4 v = *(const float4*)(src + (long)(tk*32 + row)*512 + tn*32 + c4);
      t[row][c4+0] = v.x; t[row][c4+1] = v.y; t[row][c4+2] = v.z; t[row][c4+3] = v.w;
    }
    __syncthreads();
    {
      int n = tid >> 3, k4 = (tid & 7) * 4;     // 32 n-rows x 8 h16x4
      h16x4 o = { (h16)t[k4+0][n], (h16)t[k4+1][n], (h16)t[k4+2][n], (h16)t[k4+3][n] };
      *(h16x4*)(dst + (long)(tn*32 + n)*K + tk*32 + k4) = o;
    }
  } else if (bid < 4102) {
    int b2 = bid - 3584;
    if (b2 < 512) {
      int idx = (b2*256 + tid) * 8;
      const float4* xv = (const float4*)(x + idx);
      float4 v0 = xv[0], v1 = xv[1];
      h16x8 o;
      o[0]=(h16)v0.x; o[1]=(h16)v0.y; o[2]=(h16)v0.z; o[3]=(h16)v0.w;
      o[4]=(h16)v1.x; o[5]=(h16)v1.y; o[6]=(h16)v1.z; o[7]=(h16)v1.w;
      *(h16x8*)(xh + idx) = o;
    } else {
      int i = (b2 - 512)*256 + tid;
      if (i < 1536) b3[i] = i < 512 ? bphi[i] : (i < 1024 ? bpsi[i-512] : bnode[i-1024]);
    }
  } else {
    int r = bid - 4102;            // r = b*128 + p
    int b = r >> 7;
    int i0 = pairs[r*2], i1 = pairs[r*2+1];
    const float4* f0 = (const float4*)(feat + (long)((b*64 + i0)*64 + i1) * 1024);
    const float4* f1 = (const float4*)(feat + (long)((b*64 + i1)*64 + i0) * 1024);
    float4 a = f0[tid], c = f1[tid];
    h16x4 o;
    o[0]=(h16)(0.5f*(a.x+c.x)); o[1]=(h16)(0.5f*(a.y+c.y));
    o[2]=(h16)(0.5f*(a.z+c.z)); o[3]=(h16)(0.5f*(a.w+c.w));
    *(h16x4*)(G + (long)r*1024 + tid*4) = o;
  }
}

__device__ __forceinline__ void mfma_compute(
    const h16 (*__restrict__ As)[72], const h16 (*__restrict__ Bs)[72],
    int wm, int wn, int fr, int kg, f32x4 acc[2][2]) {
#pragma unroll
  for (int kc = 0; kc < 2; ++kc) {
    int kb = kc*32 + kg;
    h16x8 fa0 = *(const h16x8*)&As[wm*32 + fr][kb];
    h16x8 fa1 = *(const h16x8*)&As[wm*32 + 16 + fr][kb];
    h16x8 fb0 = *(const h16x8*)&Bs[wn*32 + fr][kb];
    h16x8 fb1 = *(const h16x8*)&Bs[wn*32 + 16 + fr][kb];
    acc[0][0] = __builtin_amdgcn_mfma_f32_16x16x32_f16(fa0, fb0, acc[0][0], 0,0,0);
    acc[0][1] = __builtin_amdgcn_mfma_f32_16x16x32_f16(fa0, fb1, acc[0][1], 0,0,0);
    acc[1][0] = __builtin_amdgcn_mfma_f32_16x16x32_f16(fa1, fb0, acc[1][0], 0,0,0);
    acc[1][1] = __builtin_amdgcn_mfma_f32_16x16x32_f16(fa1, fb1, acc[1][1], 0,0,0);
  }
}

// Double-buffered reg-staged pipeline, ONE barrier per K-step.
#define GEMM_PIPELINE(Agp, Bgp, K)                                        \
  {                                                                       \
    h16x8 ra0 = *(const h16x8*)(Agp);                                     \
    h16x8 ra1 = *(const h16x8*)(Agp + 8);                                 \
    h16x8 rb0 = *(const h16x8*)(Bgp);                                     \
    h16x8 rb1 = *(const h16x8*)(Bgp + 8);                                 \
    *(h16x8*)&As[0][srow][skp]   = ra0;                                   \
    *(h16x8*)&As[0][srow][skp+8] = ra1;                                   \
    *(h16x8*)&Bs[0][srow][skp]   = rb0;                                   \
    *(h16x8*)&Bs[0][srow][skp+8] = rb1;                                   \
    __syncthreads();                                                      \
    int cur = 0;                                                          \
    for (int k0 = 64; k0 < (K); k0 += 64) {                               \
      ra0 = *(const h16x8*)(Agp + k0);                                    \
      ra1 = *(const h16x8*)(Agp + k0 + 8);                                \
      rb0 = *(const h16x8*)(Bgp + k0);                                    \
      rb1 = *(const h16x8*)(Bgp + k0 + 8);                                \
      mfma_compute(As[cur], Bs[cur], wm, wn, fr, kg, acc);                \
      int nxt = cur ^ 1;                                                  \
      *(h16x8*)&As[nxt][srow][skp]   = ra0;                               \
      *(h16x8*)&As[nxt][srow][skp+8] = ra1;                               \
      *(h16x8*)&Bs[nxt][srow][skp]   = rb0;                               \
      *(h16x8*)&Bs[nxt][srow][skp+8] = rb1;                               \
      __syncthreads();                                                    \
      cur = nxt;                                                          \
    }                                                                     \
    mfma_compute(As[cur], Bs[cur], wm, wn, fr, kg, acc);                  \
  }

// 320 blocks, ONE tile each (192 main + 128 edge), all co-resident (36.9 KB LDS
// -> 4 blocks/CU). GEMM phase, grid barrier, epilogue.
__global__ __launch_bounds__(256) void k_main(
    const h16* __restrict__ xh, const h16* __restrict__ W3t,
    const float* __restrict__ b3, float* __restrict__ Y, h16* __restrict__ Yh,
    const h16* __restrict__ G, const h16* __restrict__ Wrelt,
    const float* __restrict__ brel, const int* __restrict__ pairs,
    float* __restrict__ out, unsigned* cnt) {
  __shared__ __align__(16) h16 As[2][64][72];
  __shared__ __align__(16) h16 Bs[2][64][72];
  int bid = blockIdx.x, tid = threadIdx.x;
  int lane = tid & 63, wave = tid >> 6;
  int wm = wave >> 1, wn = wave & 1;
  int srow = tid >> 2, skp = (tid & 3) * 16;
  int fr = lane & 15, kg = (lane >> 4) * 8;

  // ---------------- phase A: both GEMMs, one 64x64 tile per block ----------------
  {
    const h16 *A, *Bt; const float* bias; float* C;
    int K, ldc, tileM, tileN;
    if (bid < 192) {             // Y(512x1536) = xh @ W3t^T + b3
      A = xh; Bt = W3t; bias = b3; C = Y; K = 2048; ldc = 1536;
      tileM = (bid / 24) * 64; tileN = (bid % 24) * 64;
    } else {                     // edge(1024x512) = G @ Wrelt^T + brel, 128 tiles
      int e = bid - 192;
      A = G; Bt = Wrelt; bias = brel; C = out + 32768 + 512; K = 1024; ldc = 1024;
      tileM = (e >> 3) * 64; tileN = (e & 7) * 64;
    }
    const h16* Agp = A + (long)(tileM + srow) * K + skp;
    const h16* Bgp = Bt + (long)(tileN + srow) * K + skp;
    f32x4 acc[2][2] = {};
    GEMM_PIPELINE(Agp, Bgp, K);
    int r0 = 4 * (lane >> 4), c0 = lane & 15;
    bool wantYh = (bid < 192) && (tileN < 1024);
#pragma unroll
    for (int m = 0; m < 2; ++m)
#pragma unroll
      for (int n = 0; n < 2; ++n) {
        int row = tileM + wm*32 + m*16 + r0;
        int col = tileN + wn*32 + n*16 + c0;
        float bb = bias[col];
#pragma unroll
        for (int r = 0; r < 4; ++r) {
          float v = acc[m][n][r] + bb;
          C[(long)(row + r) * ldc + col] = v;
          if (wantYh) Yh[(long)(row + r) * 1024 + col] = (h16)v;
        }
      }
  }

  // ---------------- grid barrier (320 blocks) ----------------
  __syncthreads();
  if (tid == 0) {
    __threadfence();  // release: publish GEMM outputs across XCDs
    __hip_atomic_fetch_add(cnt, 1u, __ATOMIC_ACQ_REL, __HIP_MEMORY_SCOPE_AGENT);
    while (__hip_atomic_load(cnt, __ATOMIC_ACQUIRE, __HIP_MEMORY_SCOPE_AGENT) < 320u)
      __builtin_amdgcn_s_sleep(2);
  }
  __syncthreads();

  // ---------------- phase B: scores + first half ----------------
  if (bid < 8) {
    // S_b = phi_h @ psi_h^T (64x64, K=512), fused sigmoid
    const h16* Ab = Yh + (long)bid * 64 * 1024;
    const h16* Agp = Ab + (long)srow * 1024 + skp;
    const h16* Bgp = Ab + (long)srow * 1024 + 512 + skp;
    f32x4 acc[2][2] = {};
    GEMM_PIPELINE(Agp, Bgp, 512);
    int r0 = 4 * (lane >> 4), c0 = lane & 15;
    float* ob = out + (long)bid * 4096;
#pragma unroll
    for (int m = 0; m < 2; ++m)
#pragma unroll
      for (int n = 0; n < 2; ++n) {
        int row = wm*32 + m*16 + r0;
        int col = wn*32 + n*16 + c0;
#pragma unroll
        for (int r = 0; r < 4; ++r) {
          float s = acc[m][n][r];
          ob[(long)(row + r) * 64 + col] = 1.f / (1.f + expf(-s));
        }
      }
  } else {
    // first half: 0.5*(node_emb[b,i0]+node_emb[b,i1]); 1024 units over 312 blocks
#pragma unroll 1
    for (int u = bid - 8; u < 1024; u += 312) {
      int b = u >> 7;
      int i0 = pairs[u*2], i1 = pairs[u*2+1];
      const float* n0 = Y + (long)(b*64 + i0)*1536 + 1024;
      const float* n1 = Y + (long)(b*64 + i1)*1536 + 1024;
      float* o = out + 32768 + (long)u*1024;
      for (int c = tid; c < 512; c += 256)
        o[c] = 0.5f*(n0[c] + n1[c]);
    }
  }
}

extern "C" void kernel_launch(void* const* d_in, const int* in_sizes, int n_in,
                              void* d_out, int out_size, void* d_ws, size_t ws_size,
                              hipStream_t stream) {
  const float* x     = (const float*)d_in[0];
  const float* feat  = (const float*)d_in[1];
  const float* Wphi  = (const float*)d_in[2];
  const float* bphi  = (const float*)d_in[3];
  const float* Wpsi  = (const float*)d_in[4];
  const float* bpsi  = (const float*)d_in[5];
  const float* Wnode = (const float*)d_in[6];
  const float* bnode = (const float*)d_in[7];
  const float* Wrel  = (const float*)d_in[8];
  const float* brel  = (const float*)d_in[9];
  const int*   pairs = (const int*)d_in[10];
  float* out = (float*)d_out;
  char* ws = (char*)d_ws;

  hipMemsetAsync(ws + O_CNT, 0, 4, stream);
  k_prep<<<dim3(5126), dim3(256), 0, stream>>>(
      Wphi, Wpsi, Wnode, Wrel, x, bphi, bpsi, bnode, feat, pairs,
      (h16*)(ws + O_W3T), (h16*)(ws + O_WREL), (h16*)(ws + O_XH),
      (float*)(ws + O_B3), (h16*)(ws + O_G));
  k_main<<<dim3(320), dim3(256), 0, stream>>>(
      (const h16*)(ws + O_XH), (const h16*)(ws + O_W3T), (const float*)(ws + O_B3),
      (float*)(ws + O_Y), (h16*)(ws + O_YH),
      (const h16*)(ws + O_G), (const h16*)(ws + O_WREL), brel, pairs, out,
      (unsigned*)(ws + O_CNT));
}

// Round 7
// 78.732 us; speedup vs baseline: 1.3859x; 1.3859x over previous
//
#include <hip/hip_runtime.h>
#include <hip/hip_bf16.h>

// B=8, N=64, P=128, DNODE=2048, DEDGE=1024, DEMB=512, E=32768
// edge_locating_tensor is the canonical meshgrid -> lookup(b,i,j)=b*4096+i*64+j.
// Only 2*B*P=2048 of 32768 edge rows used; (e1+e2)*0.5 folds into the GEMM input.
// Structure: k_prep (high-TLP) -> k_main (320 blocks: both GEMMs, grid barrier,
// scores+first-half).
// R6 lesson: ACQUIRE-per-poll in the spin loop emits buffer_inv per iteration ->
// continuous all-XCD L2 invalidation -> 5x latency stretch (101 us). Barrier now
// polls RELAXED and does ONE acquire after exit.

typedef _Float16 h16;
typedef h16 h16x4 __attribute__((ext_vector_type(4)));
typedef h16 h16x8 __attribute__((ext_vector_type(8)));
typedef float f32x4 __attribute__((ext_vector_type(4)));

// ---------------- ws layout (bytes) ----------------
static const long O_XH   = 0;         // 512*2048*2
static const long O_W3T  = 2097152;   // 1536*2048*2
static const long O_WREL = 8388608;   // 512*1024*2
static const long O_G    = 9437184;   // 1024*1024*2
static const long O_B3   = 11534336;  // 1536*4
static const long O_Y    = 11540480;  // 512*1536*4
static const long O_YH   = 14686208;  // 512*1024*2
static const long O_CNT  = 15734784;  // 4 (memset to 0 every call)

__global__ __launch_bounds__(256) void k_prep(
    const float* __restrict__ Wphi, const float* __restrict__ Wpsi,
    const float* __restrict__ Wnode, const float* __restrict__ Wrel,
    const float* __restrict__ x, const float* __restrict__ bphi,
    const float* __restrict__ bpsi, const float* __restrict__ bnode,
    const float* __restrict__ feat, const int* __restrict__ pairs,
    h16* __restrict__ W3t, h16* __restrict__ Wrelt, h16* __restrict__ xh,
    float* __restrict__ b3, h16* __restrict__ G) {
  __shared__ float t[32][33];
  int bid = blockIdx.x, tid = threadIdx.x;
  if (bid < 3584) {
    // weight transpose+cvt, 32x32 f32 tile: float4 loads, h16x4 stores
    const float* src; h16* dst; int K, tk, tn;
    if (bid < 3072) {
      int mat = bid >> 10, rem = bid & 1023;
      tk = rem >> 4; tn = rem & 15;
      src = mat == 0 ? Wphi : (mat == 1 ? Wpsi : Wnode);
      K = 2048; dst = W3t + (long)mat * 512 * 2048;
    } else {
      int rem = bid - 3072;
      tk = rem >> 4; tn = rem & 15;
      src = Wrel; K = 1024; dst = Wrelt;
    }
    {
      int row = tid >> 3, c4 = (tid & 7) * 4;   // 32 rows x 8 float4
      float4 v = *(const float4*)(src + (long)(tk*32 + row)*512 + tn*32 + c4);
      t[row][c4+0] = v.x; t[row][c4+1] = v.y; t[row][c4+2] = v.z; t[row][c4+3] = v.w;
    }
    __syncthreads();
    {
      int n = tid >> 3, k4 = (tid & 7) * 4;     // 32 n-rows x 8 h16x4
      h16x4 o = { (h16)t[k4+0][n], (h16)t[k4+1][n], (h16)t[k4+2][n], (h16)t[k4+3][n] };
      *(h16x4*)(dst + (long)(tn*32 + n)*K + tk*32 + k4) = o;
    }
  } else if (bid < 4102) {
    int b2 = bid - 3584;
    if (b2 < 512) {
      int idx = (b2*256 + tid) * 8;
      const float4* xv = (const float4*)(x + idx);
      float4 v0 = xv[0], v1 = xv[1];
      h16x8 o;
      o[0]=(h16)v0.x; o[1]=(h16)v0.y; o[2]=(h16)v0.z; o[3]=(h16)v0.w;
      o[4]=(h16)v1.x; o[5]=(h16)v1.y; o[6]=(h16)v1.z; o[7]=(h16)v1.w;
      *(h16x8*)(xh + idx) = o;
    } else {
      int i = (b2 - 512)*256 + tid;
      if (i < 1536) b3[i] = i < 512 ? bphi[i] : (i < 1024 ? bpsi[i-512] : bnode[i-1024]);
    }
  } else {
    int r = bid - 4102;            // r = b*128 + p
    int b = r >> 7;
    int i0 = pairs[r*2], i1 = pairs[r*2+1];
    const float4* f0 = (const float4*)(feat + (long)((b*64 + i0)*64 + i1) * 1024);
    const float4* f1 = (const float4*)(feat + (long)((b*64 + i1)*64 + i0) * 1024);
    float4 a = f0[tid], c = f1[tid];
    h16x4 o;
    o[0]=(h16)(0.5f*(a.x+c.x)); o[1]=(h16)(0.5f*(a.y+c.y));
    o[2]=(h16)(0.5f*(a.z+c.z)); o[3]=(h16)(0.5f*(a.w+c.w));
    *(h16x4*)(G + (long)r*1024 + tid*4) = o;
  }
}

__device__ __forceinline__ void mfma_compute(
    const h16 (*__restrict__ As)[72], const h16 (*__restrict__ Bs)[72],
    int wm, int wn, int fr, int kg, f32x4 acc[2][2]) {
#pragma unroll
  for (int kc = 0; kc < 2; ++kc) {
    int kb = kc*32 + kg;
    h16x8 fa0 = *(const h16x8*)&As[wm*32 + fr][kb];
    h16x8 fa1 = *(const h16x8*)&As[wm*32 + 16 + fr][kb];
    h16x8 fb0 = *(const h16x8*)&Bs[wn*32 + fr][kb];
    h16x8 fb1 = *(const h16x8*)&Bs[wn*32 + 16 + fr][kb];
    acc[0][0] = __builtin_amdgcn_mfma_f32_16x16x32_f16(fa0, fb0, acc[0][0], 0,0,0);
    acc[0][1] = __builtin_amdgcn_mfma_f32_16x16x32_f16(fa0, fb1, acc[0][1], 0,0,0);
    acc[1][0] = __builtin_amdgcn_mfma_f32_16x16x32_f16(fa1, fb0, acc[1][0], 0,0,0);
    acc[1][1] = __builtin_amdgcn_mfma_f32_16x16x32_f16(fa1, fb1, acc[1][1], 0,0,0);
  }
}

// Double-buffered reg-staged pipeline, ONE barrier per K-step.
#define GEMM_PIPELINE(Agp, Bgp, K)                                        \
  {                                                                       \
    h16x8 ra0 = *(const h16x8*)(Agp);                                     \
    h16x8 ra1 = *(const h16x8*)(Agp + 8);                                 \
    h16x8 rb0 = *(const h16x8*)(Bgp);                                     \
    h16x8 rb1 = *(const h16x8*)(Bgp + 8);                                 \
    *(h16x8*)&As[0][srow][skp]   = ra0;                                   \
    *(h16x8*)&As[0][srow][skp+8] = ra1;                                   \
    *(h16x8*)&Bs[0][srow][skp]   = rb0;                                   \
    *(h16x8*)&Bs[0][srow][skp+8] = rb1;                                   \
    __syncthreads();                                                      \
    int cur = 0;                                                          \
    for (int k0 = 64; k0 < (K); k0 += 64) {                               \
      ra0 = *(const h16x8*)(Agp + k0);                                    \
      ra1 = *(const h16x8*)(Agp + k0 + 8);                                \
      rb0 = *(const h16x8*)(Bgp + k0);                                    \
      rb1 = *(const h16x8*)(Bgp + k0 + 8);                                \
      mfma_compute(As[cur], Bs[cur], wm, wn, fr, kg, acc);                \
      int nxt = cur ^ 1;                                                  \
      *(h16x8*)&As[nxt][srow][skp]   = ra0;                               \
      *(h16x8*)&As[nxt][srow][skp+8] = ra1;                               \
      *(h16x8*)&Bs[nxt][srow][skp]   = rb0;                               \
      *(h16x8*)&Bs[nxt][srow][skp+8] = rb1;                               \
      __syncthreads();                                                    \
      cur = nxt;                                                          \
    }                                                                     \
    mfma_compute(As[cur], Bs[cur], wm, wn, fr, kg, acc);                  \
  }

// 320 blocks, ONE tile each (192 main + 128 edge), all co-resident (36.9 KB LDS
// -> 4 blocks/CU). GEMM phase, grid barrier, epilogue.
__global__ __launch_bounds__(256) void k_main(
    const h16* __restrict__ xh, const h16* __restrict__ W3t,
    const float* __restrict__ b3, float* __restrict__ Y, h16* __restrict__ Yh,
    const h16* __restrict__ G, const h16* __restrict__ Wrelt,
    const float* __restrict__ brel, const int* __restrict__ pairs,
    float* __restrict__ out, unsigned* cnt) {
  __shared__ __align__(16) h16 As[2][64][72];
  __shared__ __align__(16) h16 Bs[2][64][72];
  int bid = blockIdx.x, tid = threadIdx.x;
  int lane = tid & 63, wave = tid >> 6;
  int wm = wave >> 1, wn = wave & 1;
  int srow = tid >> 2, skp = (tid & 3) * 16;
  int fr = lane & 15, kg = (lane >> 4) * 8;

  // ---------------- phase A: both GEMMs, one 64x64 tile per block ----------------
  {
    const h16 *A, *Bt; const float* bias; float* C;
    int K, ldc, tileM, tileN;
    if (bid < 192) {             // Y(512x1536) = xh @ W3t^T + b3
      A = xh; Bt = W3t; bias = b3; C = Y; K = 2048; ldc = 1536;
      tileM = (bid / 24) * 64; tileN = (bid % 24) * 64;
    } else {                     // edge(1024x512) = G @ Wrelt^T + brel, 128 tiles
      int e = bid - 192;
      A = G; Bt = Wrelt; bias = brel; C = out + 32768 + 512; K = 1024; ldc = 1024;
      tileM = (e >> 3) * 64; tileN = (e & 7) * 64;
    }
    const h16* Agp = A + (long)(tileM + srow) * K + skp;
    const h16* Bgp = Bt + (long)(tileN + srow) * K + skp;
    f32x4 acc[2][2] = {};
    GEMM_PIPELINE(Agp, Bgp, K);
    int r0 = 4 * (lane >> 4), c0 = lane & 15;
    bool wantYh = (bid < 192) && (tileN < 1024);
#pragma unroll
    for (int m = 0; m < 2; ++m)
#pragma unroll
      for (int n = 0; n < 2; ++n) {
        int row = tileM + wm*32 + m*16 + r0;
        int col = tileN + wn*32 + n*16 + c0;
        float bb = bias[col];
#pragma unroll
        for (int r = 0; r < 4; ++r) {
          float v = acc[m][n][r] + bb;
          C[(long)(row + r) * ldc + col] = v;
          if (wantYh) Yh[(long)(row + r) * 1024 + col] = (h16)v;
        }
      }
  }

  // ------- grid barrier (320 blocks): RELAXED spin, ONE acquire at exit -------
  __syncthreads();
  if (tid == 0) {
    __threadfence();  // release: write back phase-A stores device-wide
    __hip_atomic_fetch_add(cnt, 1u, __ATOMIC_RELEASE, __HIP_MEMORY_SCOPE_AGENT);
    while (__hip_atomic_load(cnt, __ATOMIC_RELAXED, __HIP_MEMORY_SCOPE_AGENT) < 320u)
      __builtin_amdgcn_s_sleep(64);
    // single cache-invalidate AFTER the barrier opens (R6: per-poll acquire
    // emitted buffer_inv per iteration -> all-XCD L2 thrash, 5x stretch)
    (void)__hip_atomic_load(cnt, __ATOMIC_ACQUIRE, __HIP_MEMORY_SCOPE_AGENT);
  }
  __syncthreads();

  // ---------------- phase B: scores + first half ----------------
  if (bid < 8) {
    // S_b = phi_h @ psi_h^T (64x64, K=512), fused sigmoid
    const h16* Ab = Yh + (long)bid * 64 * 1024;
    const h16* Agp = Ab + (long)srow * 1024 + skp;
    const h16* Bgp = Ab + (long)srow * 1024 + 512 + skp;
    f32x4 acc[2][2] = {};
    GEMM_PIPELINE(Agp, Bgp, 512);
    int r0 = 4 * (lane >> 4), c0 = lane & 15;
    float* ob = out + (long)bid * 4096;
#pragma unroll
    for (int m = 0; m < 2; ++m)
#pragma unroll
      for (int n = 0; n < 2; ++n) {
        int row = wm*32 + m*16 + r0;
        int col = wn*32 + n*16 + c0;
#pragma unroll
        for (int r = 0; r < 4; ++r) {
          float s = acc[m][n][r];
          ob[(long)(row + r) * 64 + col] = 1.f / (1.f + expf(-s));
        }
      }
  } else {
    // first half: 0.5*(node_emb[b,i0]+node_emb[b,i1]); 1024 units over 312 blocks
#pragma unroll 1
    for (int u = bid - 8; u < 1024; u += 312) {
      int b = u >> 7;
      int i0 = pairs[u*2], i1 = pairs[u*2+1];
      const float* n0 = Y + (long)(b*64 + i0)*1536 + 1024;
      const float* n1 = Y + (long)(b*64 + i1)*1536 + 1024;
      float* o = out + 32768 + (long)u*1024;
      for (int c = tid; c < 512; c += 256)
        o[c] = 0.5f*(n0[c] + n1[c]);
    }
  }
}

extern "C" void kernel_launch(void* const* d_in, const int* in_sizes, int n_in,
                              void* d_out, int out_size, void* d_ws, size_t ws_size,
                              hipStream_t stream) {
  const float* x     = (const float*)d_in[0];
  const float* feat  = (const float*)d_in[1];
  const float* Wphi  = (const float*)d_in[2];
  const float* bphi  = (const float*)d_in[3];
  const float* Wpsi  = (const float*)d_in[4];
  const float* bpsi  = (const float*)d_in[5];
  const float* Wnode = (const float*)d_in[6];
  const float* bnode = (const float*)d_in[7];
  const float* Wrel  = (const float*)d_in[8];
  const float* brel  = (const float*)d_in[9];
  const int*   pairs = (const int*)d_in[10];
  float* out = (float*)d_out;
  char* ws = (char*)d_ws;

  hipMemsetAsync(ws + O_CNT, 0, 4, stream);
  k_prep<<<dim3(5126), dim3(256), 0, stream>>>(
      Wphi, Wpsi, Wnode, Wrel, x, bphi, bpsi, bnode, feat, pairs,
      (h16*)(ws + O_W3T), (h16*)(ws + O_WREL), (h16*)(ws + O_XH),
      (float*)(ws + O_B3), (h16*)(ws + O_G));
  k_main<<<dim3(320), dim3(256), 0, stream>>>(
      (const h16*)(ws + O_XH), (const h16*)(ws + O_W3T), (const float*)(ws + O_B3),
      (float*)(ws + O_Y), (h16*)(ws + O_YH),
      (const h16*)(ws + O_G), (const h16*)(ws + O_WREL), brel, pairs, out,
      (unsigned*)(ws + O_CNT));
}

// Round 8
// 58.856 us; speedup vs baseline: 1.8539x; 1.3377x over previous
//
#include <hip/hip_runtime.h>
#include <hip/hip_bf16.h>

// B=8, N=64, P=128, DNODE=2048, DEDGE=1024, DEMB=512, E=32768
// lookup(b,i,j) = b*4096+i*64+j (canonical meshgrid); only 2048 of 32768 edge
// rows used; (e1+e2)*0.5 folds into the GEMM input (linearity, bias once).
// R7 lesson: cross-XCD sw barriers cost ~30+us (wbl2/inv tag-scans serialize
// at L2) -> use kernel boundaries. This round: prep ELIMINATED by fusing
// cvt/gather into GEMM staging; B staged column-per-thread (coalesced row
// reads across lanes, contiguous LDS writes) so no W transpose ever exists.
// 2 dispatches: k_gemm (256 blocks, raw inputs) -> k_epilogue.

typedef _Float16 h16;
typedef h16 h16x4 __attribute__((ext_vector_type(4)));
typedef h16 h16x8 __attribute__((ext_vector_type(8)));
typedef float f32x4 __attribute__((ext_vector_type(4)));

// ws: Y fp32 [512][1536] at 0; Yh f16 [512][1024] at 3145728
static const long O_Y  = 0;
static const long O_YH = 3145728;

__device__ __forceinline__ void mfma_compute(
    const h16 (*__restrict__ As)[72], const h16 (*__restrict__ Bs)[72],
    int wm, int wn, int fr, int kg, f32x4 acc[2][2]) {
#pragma unroll
  for (int kc = 0; kc < 2; ++kc) {
    int kb = kc*32 + kg;
    h16x8 fa0 = *(const h16x8*)&As[wm*32 + fr][kb];
    h16x8 fa1 = *(const h16x8*)&As[wm*32 + 16 + fr][kb];
    h16x8 fb0 = *(const h16x8*)&Bs[wn*32 + fr][kb];
    h16x8 fb1 = *(const h16x8*)&Bs[wn*32 + 16 + fr][kb];
    acc[0][0] = __builtin_amdgcn_mfma_f32_16x16x32_f16(fa0, fb0, acc[0][0], 0,0,0);
    acc[0][1] = __builtin_amdgcn_mfma_f32_16x16x32_f16(fa0, fb1, acc[0][1], 0,0,0);
    acc[1][0] = __builtin_amdgcn_mfma_f32_16x16x32_f16(fa1, fb0, acc[1][0], 0,0,0);
    acc[1][1] = __builtin_amdgcn_mfma_f32_16x16x32_f16(fa1, fb1, acc[1][1], 0,0,0);
  }
}

// ---- fused-staging GEMM: A rows fp32 (x or avg of two feat rows), B cols fp32
// (W with row stride 512). Staged as f16 into the SAME LDS layout/fragments as
// the verified R3 kernel. Per-thread regs for chunk t+1 loaded before compute t.
#define LD4(p) (*(const float4*)(p))

#define LOADREGS(k0_)                                                     \
  {                                                                       \
    const float* pa = arow0 + (k0_) + kseg;                               \
    a0_ = LD4(pa); a1_ = LD4(pa+4); a2_ = LD4(pa+8); a3_ = LD4(pa+12);    \
    if (isEdge) {                                                         \
      const float* pq = arow1 + (k0_) + kseg;                             \
      float4 q0 = LD4(pq), q1 = LD4(pq+4), q2 = LD4(pq+8), q3 = LD4(pq+12);\
      a0_.x=0.5f*(a0_.x+q0.x); a0_.y=0.5f*(a0_.y+q0.y); a0_.z=0.5f*(a0_.z+q0.z); a0_.w=0.5f*(a0_.w+q0.w); \
      a1_.x=0.5f*(a1_.x+q1.x); a1_.y=0.5f*(a1_.y+q1.y); a1_.z=0.5f*(a1_.z+q1.z); a1_.w=0.5f*(a1_.w+q1.w); \
      a2_.x=0.5f*(a2_.x+q2.x); a2_.y=0.5f*(a2_.y+q2.y); a2_.z=0.5f*(a2_.z+q2.z); a2_.w=0.5f*(a2_.w+q2.w); \
      a3_.x=0.5f*(a3_.x+q3.x); a3_.y=0.5f*(a3_.y+q3.y); a3_.z=0.5f*(a3_.z+q3.z); a3_.w=0.5f*(a3_.w+q3.w); \
    }                                                                     \
    const float* pb = bcol + (long)((k0_) + kblk) * 512;                  \
    _Pragma("unroll")                                                     \
    for (int i = 0; i < 16; ++i) b_[i] = pb[(long)i * 512];               \
  }

#define WRITEREGS(bufi)                                                   \
  {                                                                       \
    h16x8 wa0, wa1;                                                       \
    wa0[0]=(h16)a0_.x; wa0[1]=(h16)a0_.y; wa0[2]=(h16)a0_.z; wa0[3]=(h16)a0_.w; \
    wa0[4]=(h16)a1_.x; wa0[5]=(h16)a1_.y; wa0[6]=(h16)a1_.z; wa0[7]=(h16)a1_.w; \
    wa1[0]=(h16)a2_.x; wa1[1]=(h16)a2_.y; wa1[2]=(h16)a2_.z; wa1[3]=(h16)a2_.w; \
    wa1[4]=(h16)a3_.x; wa1[5]=(h16)a3_.y; wa1[6]=(h16)a3_.z; wa1[7]=(h16)a3_.w; \
    *(h16x8*)&As[bufi][srow][kseg]     = wa0;                             \
    *(h16x8*)&As[bufi][srow][kseg + 8] = wa1;                             \
    h16x8 wb0, wb1;                                                       \
    wb0[0]=(h16)b_[0]; wb0[1]=(h16)b_[1]; wb0[2]=(h16)b_[2]; wb0[3]=(h16)b_[3]; \
    wb0[4]=(h16)b_[4]; wb0[5]=(h16)b_[5]; wb0[6]=(h16)b_[6]; wb0[7]=(h16)b_[7]; \
    wb1[0]=(h16)b_[8]; wb1[1]=(h16)b_[9]; wb1[2]=(h16)b_[10]; wb1[3]=(h16)b_[11]; \
    wb1[4]=(h16)b_[12]; wb1[5]=(h16)b_[13]; wb1[6]=(h16)b_[14]; wb1[7]=(h16)b_[15]; \
    *(h16x8*)&Bs[bufi][ncol][kblk]     = wb0;                             \
    *(h16x8*)&Bs[bufi][ncol][kblk + 8] = wb1;                             \
  }

__global__ __launch_bounds__(256) void k_gemm(
    const float* __restrict__ x, const float* __restrict__ feat,
    const float* __restrict__ Wphi, const float* __restrict__ Wpsi,
    const float* __restrict__ Wnode, const float* __restrict__ bphi,
    const float* __restrict__ bpsi, const float* __restrict__ bnode,
    const float* __restrict__ Wrel, const float* __restrict__ brel,
    const int* __restrict__ pairs,
    float* __restrict__ Y, h16* __restrict__ Yh, float* __restrict__ out) {
  __shared__ __align__(16) h16 As[2][64][72];
  __shared__ __align__(16) h16 Bs[2][64][72];
  int bid = blockIdx.x, tid = threadIdx.x;
  int lane = tid & 63, wave = tid >> 6;
  int wm = wave >> 1, wn = wave & 1;
  int srow = tid >> 2, kseg = (tid & 3) * 16;   // A staging: row, k-segment
  int ncol = tid & 63, kblk = (tid >> 6) * 16;  // B staging: col, k-block
  int fr = lane & 15, kg = (lane >> 4) * 8;

  int isEdge = bid >= 192;
  int ntile = isEdge ? 2 : 1;
#pragma unroll 1
  for (int ti = 0; ti < ntile; ++ti) {
    if (ti) __syncthreads();
    int K, tileM, tileN;
    const float *arow0, *arow1, *bcol;
    if (!isEdge) {               // Y(512x1536) = x @ [Wphi|Wpsi|Wnode] + bias
      K = 2048; tileM = (bid / 24) * 64; tileN = (bid % 24) * 64;
      arow0 = arow1 = x + (long)(tileM + srow) * 2048;
      int mat = tileN >> 9;
      const float* Wm = mat == 0 ? Wphi : (mat == 1 ? Wpsi : Wnode);
      bcol = Wm + (tileN & 511) + ncol;
    } else {                     // edge(1024x512) = avgfeat @ Wrel + brel
      int e = (bid - 192) * 2 + ti;           // 64 blocks x 2 = 128 tiles
      K = 1024; tileM = (e >> 3) * 64; tileN = (e & 7) * 64;
      int r = tileM + srow, b = r >> 7;
      int i0 = pairs[r*2], i1 = pairs[r*2+1];
      arow0 = feat + (long)((b*64 + i0)*64 + i1) * 1024;
      arow1 = feat + (long)((b*64 + i1)*64 + i0) * 1024;
      bcol = Wrel + tileN + ncol;
    }
    float4 a0_, a1_, a2_, a3_; float b_[16];
    f32x4 acc[2][2] = {};
    LOADREGS(0)
    WRITEREGS(0)
    __syncthreads();
    int cur = 0;
#pragma unroll 1
    for (int k0 = 64; k0 < K; k0 += 64) {
      LOADREGS(k0)
      mfma_compute(As[cur], Bs[cur], wm, wn, fr, kg, acc);
      WRITEREGS(cur ^ 1)
      __syncthreads();
      cur ^= 1;
    }
    mfma_compute(As[cur], Bs[cur], wm, wn, fr, kg, acc);

    int r0 = 4 * (lane >> 4), c0 = lane & 15;
#pragma unroll
    for (int m = 0; m < 2; ++m)
#pragma unroll
      for (int n = 0; n < 2; ++n) {
        int row = tileM + wm*32 + m*16 + r0;
        int col = tileN + wn*32 + n*16 + c0;
        if (!isEdge) {
          float bb = col < 512 ? bphi[col] : (col < 1024 ? bpsi[col-512] : bnode[col-1024]);
#pragma unroll
          for (int r = 0; r < 4; ++r) {
            float v = acc[m][n][r] + bb;
            Y[(long)(row + r) * 1536 + col] = v;
            if (col < 1024) Yh[(long)(row + r) * 1024 + col] = (h16)v;
          }
        } else {
          float bb = brel[col];
#pragma unroll
          for (int r = 0; r < 4; ++r)
            out[32768 + 512 + (long)(row + r) * 1024 + col] = acc[m][n][r] + bb;
        }
      }
  }
}

// ---- epilogue: h16 reg-prefetch pipeline (verified R3 path) for scores ----
#define GEMM_PIPELINE_H16(Agp, Bgp, K)                                    \
  {                                                                       \
    h16x8 ra0 = *(const h16x8*)(Agp);                                     \
    h16x8 ra1 = *(const h16x8*)(Agp + 8);                                 \
    h16x8 rb0 = *(const h16x8*)(Bgp);                                     \
    h16x8 rb1 = *(const h16x8*)(Bgp + 8);                                 \
    *(h16x8*)&As[0][srow][skp]   = ra0;                                   \
    *(h16x8*)&As[0][srow][skp+8] = ra1;                                   \
    *(h16x8*)&Bs[0][srow][skp]   = rb0;                                   \
    *(h16x8*)&Bs[0][srow][skp+8] = rb1;                                   \
    __syncthreads();                                                      \
    int cur = 0;                                                          \
    for (int k0 = 64; k0 < (K); k0 += 64) {                               \
      ra0 = *(const h16x8*)(Agp + k0);                                    \
      ra1 = *(const h16x8*)(Agp + k0 + 8);                                \
      rb0 = *(const h16x8*)(Bgp + k0);                                    \
      rb1 = *(const h16x8*)(Bgp + k0 + 8);                                \
      mfma_compute(As[cur], Bs[cur], wm, wn, fr, kg, acc);                \
      int nxt = cur ^ 1;                                                  \
      *(h16x8*)&As[nxt][srow][skp]   = ra0;                               \
      *(h16x8*)&As[nxt][srow][skp+8] = ra1;                               \
      *(h16x8*)&Bs[nxt][srow][skp]   = rb0;                               \
      *(h16x8*)&Bs[nxt][srow][skp+8] = rb1;                               \
      __syncthreads();                                                    \
      cur = nxt;                                                          \
    }                                                                     \
    mfma_compute(As[cur], Bs[cur], wm, wn, fr, kg, acc);                  \
  }

// blocks 0..7: scores = sigmoid(phi_h @ psi_h^T) per batch; 8..1031: first half.
__global__ __launch_bounds__(256) void k_epilogue(
    const float* __restrict__ Y, const h16* __restrict__ Yh,
    const int* __restrict__ pairs, float* __restrict__ out) {
  __shared__ __align__(16) h16 As[2][64][72];
  __shared__ __align__(16) h16 Bs[2][64][72];
  int bid = blockIdx.x, tid = threadIdx.x;
  if (bid < 8) {
    int lane = tid & 63, wave = tid >> 6;
    int wm = wave >> 1, wn = wave & 1;
    int srow = tid >> 2, skp = (tid & 3) * 16;
    int fr = lane & 15, kg = (lane >> 4) * 8;
    const h16* Ab = Yh + (long)bid * 64 * 1024;
    const h16* Agp = Ab + (long)srow * 1024 + skp;         // phi rows
    const h16* Bgp = Ab + (long)srow * 1024 + 512 + skp;   // psi rows
    f32x4 acc[2][2] = {};
    GEMM_PIPELINE_H16(Agp, Bgp, 512);
    int r0 = 4 * (lane >> 4), c0 = lane & 15;
    float* ob = out + (long)bid * 4096;
#pragma unroll
    for (int m = 0; m < 2; ++m)
#pragma unroll
      for (int n = 0; n < 2; ++n) {
        int row = wm*32 + m*16 + r0;
        int col = wn*32 + n*16 + c0;
#pragma unroll
        for (int r = 0; r < 4; ++r) {
          float s = acc[m][n][r];
          ob[(long)(row + r) * 64 + col] = 1.f / (1.f + expf(-s));
        }
      }
  } else {
    int r = bid - 8;
    int b = r >> 7;
    int i0 = pairs[r*2], i1 = pairs[r*2+1];
    const float* n0 = Y + (long)(b*64 + i0)*1536 + 1024;
    const float* n1 = Y + (long)(b*64 + i1)*1536 + 1024;
    float* o = out + 32768 + (long)r*1024;
    for (int c = tid; c < 512; c += 256)
      o[c] = 0.5f*(n0[c] + n1[c]);
  }
}

extern "C" void kernel_launch(void* const* d_in, const int* in_sizes, int n_in,
                              void* d_out, int out_size, void* d_ws, size_t ws_size,
                              hipStream_t stream) {
  const float* x     = (const float*)d_in[0];
  const float* feat  = (const float*)d_in[1];
  const float* Wphi  = (const float*)d_in[2];
  const float* bphi  = (const float*)d_in[3];
  const float* Wpsi  = (const float*)d_in[4];
  const float* bpsi  = (const float*)d_in[5];
  const float* Wnode = (const float*)d_in[6];
  const float* bnode = (const float*)d_in[7];
  const float* Wrel  = (const float*)d_in[8];
  const float* brel  = (const float*)d_in[9];
  const int*   pairs = (const int*)d_in[10];
  float* out = (float*)d_out;
  char* ws = (char*)d_ws;

  float* Y  = (float*)(ws + O_Y);
  h16*   Yh = (h16*)(ws + O_YH);

  k_gemm<<<dim3(256), dim3(256), 0, stream>>>(
      x, feat, Wphi, Wpsi, Wnode, bphi, bpsi, bnode, Wrel, brel, pairs,
      Y, Yh, out);
  k_epilogue<<<dim3(1032), dim3(256), 0, stream>>>(Y, Yh, pairs, out);
}

// Round 9
// 55.469 us; speedup vs baseline: 1.9671x; 1.0611x over previous
//
#include <hip/hip_runtime.h>
#include <hip/hip_bf16.h>

// B=8, N=64, P=128, DNODE=2048, DEDGE=1024, DEMB=512, E=32768
// lookup(b,i,j)=b*4096+i*64+j (canonical meshgrid); only 2048 of 32768 edge
// rows used; (e1+e2)*0.5 folds into the GEMM A-side (linearity, bias once).
// R8 lesson: B-side fused staging = 16 scalar VMEM/thread/step -> keep W
// transpose in prep (amortized over 8 panel re-reads). A-side fusion is cheap
// (row-major float4) -> x-cvt and pair-gather live in GEMM staging.
// 3 nodes: k_prep (W transpose, 3584 blocks) -> k_gemm (256 balanced blocks)
// -> k_epilogue (scores MFMA + first half). All intermediates f16.

typedef _Float16 h16;
typedef h16 h16x4 __attribute__((ext_vector_type(4)));
typedef h16 h16x8 __attribute__((ext_vector_type(8)));
typedef float f32x4 __attribute__((ext_vector_type(4)));

// ws layout: W3t f16 [1536][2048] at 0 ; Wrelt f16 [512][1024] at 6291456 ;
//            Yh f16 [512][1536] at 7340032   (phi|psi|node)
static const long O_W3T  = 0;
static const long O_WREL = 6291456;
static const long O_YH   = 7340032;

// ---------------- prep: weight transpose+cvt only ----------------
__global__ __launch_bounds__(256) void k_prep(
    const float* __restrict__ Wphi, const float* __restrict__ Wpsi,
    const float* __restrict__ Wnode, const float* __restrict__ Wrel,
    h16* __restrict__ W3t, h16* __restrict__ Wrelt) {
  __shared__ float t[32][33];
  int bid = blockIdx.x, tid = threadIdx.x;
  const float* src; h16* dst; int K, tk, tn;
  if (bid < 3072) {
    int mat = bid >> 10, rem = bid & 1023;
    tk = rem >> 4; tn = rem & 15;
    src = mat == 0 ? Wphi : (mat == 1 ? Wpsi : Wnode);
    K = 2048; dst = W3t + (long)mat * 512 * 2048;
  } else {
    int rem = bid - 3072;
    tk = rem >> 4; tn = rem & 15;
    src = Wrel; K = 1024; dst = Wrelt;
  }
  {
    int row = tid >> 3, c4 = (tid & 7) * 4;   // 32 rows x 8 float4
    float4 v = *(const float4*)(src + (long)(tk*32 + row)*512 + tn*32 + c4);
    t[row][c4+0] = v.x; t[row][c4+1] = v.y; t[row][c4+2] = v.z; t[row][c4+3] = v.w;
  }
  __syncthreads();
  {
    int n = tid >> 3, k4 = (tid & 7) * 4;     // 32 n-rows x 8 h16x4
    h16x4 o = { (h16)t[k4+0][n], (h16)t[k4+1][n], (h16)t[k4+2][n], (h16)t[k4+3][n] };
    *(h16x4*)(dst + (long)(tn*32 + n)*K + tk*32 + k4) = o;
  }
}

__device__ __forceinline__ void mfma_compute(
    const h16 (*__restrict__ As)[72], const h16 (*__restrict__ Bs)[72],
    int wm, int wn, int fr, int kg, f32x4 acc[2][2]) {
#pragma unroll
  for (int kc = 0; kc < 2; ++kc) {
    int kb = kc*32 + kg;
    h16x8 fa0 = *(const h16x8*)&As[wm*32 + fr][kb];
    h16x8 fa1 = *(const h16x8*)&As[wm*32 + 16 + fr][kb];
    h16x8 fb0 = *(const h16x8*)&Bs[wn*32 + fr][kb];
    h16x8 fb1 = *(const h16x8*)&Bs[wn*32 + 16 + fr][kb];
    acc[0][0] = __builtin_amdgcn_mfma_f32_16x16x32_f16(fa0, fb0, acc[0][0], 0,0,0);
    acc[0][1] = __builtin_amdgcn_mfma_f32_16x16x32_f16(fa0, fb1, acc[0][1], 0,0,0);
    acc[1][0] = __builtin_amdgcn_mfma_f32_16x16x32_f16(fa1, fb0, acc[1][0], 0,0,0);
    acc[1][1] = __builtin_amdgcn_mfma_f32_16x16x32_f16(fa1, fb1, acc[1][1], 0,0,0);
  }
}

#define LD4(p) (*(const float4*)(p))

// A side: fp32 (x row, or avg of two feat rows); B side: h16x8 from W3t/Wrelt.
#define LOADREGS(k0_)                                                     \
  {                                                                       \
    const float* pa = arow0 + (k0_);                                      \
    a0_ = LD4(pa); a1_ = LD4(pa+4); a2_ = LD4(pa+8); a3_ = LD4(pa+12);    \
    if (isEdge) {                                                         \
      const float* pq = arow1 + (k0_);                                    \
      float4 q0 = LD4(pq), q1 = LD4(pq+4), q2 = LD4(pq+8), q3 = LD4(pq+12);\
      a0_.x=0.5f*(a0_.x+q0.x); a0_.y=0.5f*(a0_.y+q0.y); a0_.z=0.5f*(a0_.z+q0.z); a0_.w=0.5f*(a0_.w+q0.w); \
      a1_.x=0.5f*(a1_.x+q1.x); a1_.y=0.5f*(a1_.y+q1.y); a1_.z=0.5f*(a1_.z+q1.z); a1_.w=0.5f*(a1_.w+q1.w); \
      a2_.x=0.5f*(a2_.x+q2.x); a2_.y=0.5f*(a2_.y+q2.y); a2_.z=0.5f*(a2_.z+q2.z); a2_.w=0.5f*(a2_.w+q2.w); \
      a3_.x=0.5f*(a3_.x+q3.x); a3_.y=0.5f*(a3_.y+q3.y); a3_.z=0.5f*(a3_.z+q3.z); a3_.w=0.5f*(a3_.w+q3.w); \
    }                                                                     \
    rb0 = *(const h16x8*)(Bgp + (k0_));                                   \
    rb1 = *(const h16x8*)(Bgp + (k0_) + 8);                               \
  }

#define WRITEREGS(bufi)                                                   \
  {                                                                       \
    h16x8 wa0, wa1;                                                       \
    wa0[0]=(h16)a0_.x; wa0[1]=(h16)a0_.y; wa0[2]=(h16)a0_.z; wa0[3]=(h16)a0_.w; \
    wa0[4]=(h16)a1_.x; wa0[5]=(h16)a1_.y; wa0[6]=(h16)a1_.z; wa0[7]=(h16)a1_.w; \
    wa1[0]=(h16)a2_.x; wa1[1]=(h16)a2_.y; wa1[2]=(h16)a2_.z; wa1[3]=(h16)a2_.w; \
    wa1[4]=(h16)a3_.x; wa1[5]=(h16)a3_.y; wa1[6]=(h16)a3_.z; wa1[7]=(h16)a3_.w; \
    *(h16x8*)&As[bufi][srow][skp]     = wa0;                              \
    *(h16x8*)&As[bufi][srow][skp + 8] = wa1;                              \
    *(h16x8*)&Bs[bufi][srow][skp]     = rb0;                              \
    *(h16x8*)&Bs[bufi][srow][skp + 8] = rb1;                              \
  }

// 256 blocks, balanced: 192 main tiles (K=2048, 32 steps) + 64 blocks x 2 edge
// tiles (K=1024, 2x16 steps).
__global__ __launch_bounds__(256) void k_gemm(
    const float* __restrict__ x, const float* __restrict__ feat,
    const h16* __restrict__ W3t, const h16* __restrict__ Wrelt,
    const float* __restrict__ bphi, const float* __restrict__ bpsi,
    const float* __restrict__ bnode, const float* __restrict__ brel,
    const int* __restrict__ pairs,
    h16* __restrict__ Yh, float* __restrict__ out) {
  __shared__ __align__(16) h16 As[2][64][72];
  __shared__ __align__(16) h16 Bs[2][64][72];
  int bid = blockIdx.x, tid = threadIdx.x;
  int lane = tid & 63, wave = tid >> 6;
  int wm = wave >> 1, wn = wave & 1;
  int srow = tid >> 2, skp = (tid & 3) * 16;
  int fr = lane & 15, kg = (lane >> 4) * 8;

  int isEdge = bid >= 192;
  int ntile = isEdge ? 2 : 1;
#pragma unroll 1
  for (int ti = 0; ti < ntile; ++ti) {
    if (ti) __syncthreads();
    int K, tileM, tileN;
    const float *arow0, *arow1 = nullptr;
    const h16* Bgp;
    if (!isEdge) {               // Yh(512x1536) = x @ [Wphi|Wpsi|Wnode] + bias
      K = 2048; tileM = (bid / 24) * 64; tileN = (bid % 24) * 64;
      arow0 = x + (long)(tileM + srow) * 2048 + skp;
      Bgp = W3t + (long)(tileN + srow) * 2048 + skp;
    } else {                     // edge(1024x512) = avgfeat @ Wrel^T + brel
      int e = (bid - 192) * 2 + ti;           // 128 tiles
      K = 1024; tileM = (e >> 3) * 64; tileN = (e & 7) * 64;
      int r = tileM + srow, b = r >> 7;
      int i0 = pairs[r*2], i1 = pairs[r*2+1];
      arow0 = feat + (long)((b*64 + i0)*64 + i1) * 1024 + skp;
      arow1 = feat + (long)((b*64 + i1)*64 + i0) * 1024 + skp;
      Bgp = Wrelt + (long)(tileN + srow) * 1024 + skp;
    }
    float4 a0_, a1_, a2_, a3_; h16x8 rb0, rb1;
    f32x4 acc[2][2] = {};
    LOADREGS(0)
    WRITEREGS(0)
    __syncthreads();
    int cur = 0;
#pragma unroll 1
    for (int k0 = 64; k0 < K; k0 += 64) {
      LOADREGS(k0)
      mfma_compute(As[cur], Bs[cur], wm, wn, fr, kg, acc);
      WRITEREGS(cur ^ 1)
      __syncthreads();
      cur ^= 1;
    }
    mfma_compute(As[cur], Bs[cur], wm, wn, fr, kg, acc);

    int r0 = 4 * (lane >> 4), c0 = lane & 15;
#pragma unroll
    for (int m = 0; m < 2; ++m)
#pragma unroll
      for (int n = 0; n < 2; ++n) {
        int row = tileM + wm*32 + m*16 + r0;
        int col = tileN + wn*32 + n*16 + c0;
        if (!isEdge) {
          float bb = col < 512 ? bphi[col] : (col < 1024 ? bpsi[col-512] : bnode[col-1024]);
#pragma unroll
          for (int r = 0; r < 4; ++r)
            Yh[(long)(row + r) * 1536 + col] = (h16)(acc[m][n][r] + bb);
        } else {
          float bb = brel[col];
#pragma unroll
          for (int r = 0; r < 4; ++r)
            out[32768 + 512 + (long)(row + r) * 1024 + col] = acc[m][n][r] + bb;
        }
      }
  }
}

// h16 reg-prefetch pipeline for the scores GEMM (verified R3 path).
#define GEMM_PIPELINE_H16(Agp, Bgp, K)                                    \
  {                                                                       \
    h16x8 ra0 = *(const h16x8*)(Agp);                                     \
    h16x8 ra1 = *(const h16x8*)(Agp + 8);                                 \
    h16x8 rb0 = *(const h16x8*)(Bgp);                                     \
    h16x8 rb1 = *(const h16x8*)(Bgp + 8);                                 \
    *(h16x8*)&As[0][srow][skp]   = ra0;                                   \
    *(h16x8*)&As[0][srow][skp+8] = ra1;                                   \
    *(h16x8*)&Bs[0][srow][skp]   = rb0;                                   \
    *(h16x8*)&Bs[0][srow][skp+8] = rb1;                                   \
    __syncthreads();                                                      \
    int cur = 0;                                                          \
    for (int k0 = 64; k0 < (K); k0 += 64) {                               \
      ra0 = *(const h16x8*)(Agp + k0);                                    \
      ra1 = *(const h16x8*)(Agp + k0 + 8);                                \
      rb0 = *(const h16x8*)(Bgp + k0);                                    \
      rb1 = *(const h16x8*)(Bgp + k0 + 8);                                \
      mfma_compute(As[cur], Bs[cur], wm, wn, fr, kg, acc);                \
      int nxt = cur ^ 1;                                                  \
      *(h16x8*)&As[nxt][srow][skp]   = ra0;                               \
      *(h16x8*)&As[nxt][srow][skp+8] = ra1;                               \
      *(h16x8*)&Bs[nxt][srow][skp]   = rb0;                               \
      *(h16x8*)&Bs[nxt][srow][skp+8] = rb1;                               \
      __syncthreads();                                                    \
      cur = nxt;                                                          \
    }                                                                     \
    mfma_compute(As[cur], Bs[cur], wm, wn, fr, kg, acc);                  \
  }

// blocks 0..7: scores = sigmoid(phi_h @ psi_h^T); 8..1031: first half from Yh.
__global__ __launch_bounds__(256) void k_epilogue(
    const h16* __restrict__ Yh, const int* __restrict__ pairs,
    float* __restrict__ out) {
  __shared__ __align__(16) h16 As[2][64][72];
  __shared__ __align__(16) h16 Bs[2][64][72];
  int bid = blockIdx.x, tid = threadIdx.x;
  if (bid < 8) {
    int lane = tid & 63, wave = tid >> 6;
    int wm = wave >> 1, wn = wave & 1;
    int srow = tid >> 2, skp = (tid & 3) * 16;
    int fr = lane & 15, kg = (lane >> 4) * 8;
    const h16* Ab = Yh + (long)bid * 64 * 1536;
    const h16* Agp = Ab + (long)srow * 1536 + skp;         // phi rows
    const h16* Bgp = Ab + (long)srow * 1536 + 512 + skp;   // psi rows
    f32x4 acc[2][2] = {};
    GEMM_PIPELINE_H16(Agp, Bgp, 512);
    int r0 = 4 * (lane >> 4), c0 = lane & 15;
    float* ob = out + (long)bid * 4096;
#pragma unroll
    for (int m = 0; m < 2; ++m)
#pragma unroll
      for (int n = 0; n < 2; ++n) {
        int row = wm*32 + m*16 + r0;
        int col = wn*32 + n*16 + c0;
#pragma unroll
        for (int r = 0; r < 4; ++r) {
          float s = acc[m][n][r];
          ob[(long)(row + r) * 64 + col] = 1.f / (1.f + expf(-s));
        }
      }
  } else {
    int r = bid - 8;
    int b = r >> 7;
    int i0 = pairs[r*2], i1 = pairs[r*2+1];
    const h16* n0 = Yh + (long)(b*64 + i0)*1536 + 1024;
    const h16* n1 = Yh + (long)(b*64 + i1)*1536 + 1024;
    float* o = out + 32768 + (long)r*1024;
    for (int c = tid; c < 512; c += 256)
      o[c] = 0.5f*((float)n0[c] + (float)n1[c]);
  }
}

extern "C" void kernel_launch(void* const* d_in, const int* in_sizes, int n_in,
                              void* d_out, int out_size, void* d_ws, size_t ws_size,
                              hipStream_t stream) {
  const float* x     = (const float*)d_in[0];
  const float* feat  = (const float*)d_in[1];
  const float* Wphi  = (const float*)d_in[2];
  const float* bphi  = (const float*)d_in[3];
  const float* Wpsi  = (const float*)d_in[4];
  const float* bpsi  = (const float*)d_in[5];
  const float* Wnode = (const float*)d_in[6];
  const float* bnode = (const float*)d_in[7];
  const float* Wrel  = (const float*)d_in[8];
  const float* brel  = (const float*)d_in[9];
  const int*   pairs = (const int*)d_in[10];
  float* out = (float*)d_out;
  char* ws = (char*)d_ws;

  h16* W3t   = (h16*)(ws + O_W3T);
  h16* Wrelt = (h16*)(ws + O_WREL);
  h16* Yh    = (h16*)(ws + O_YH);

  k_prep<<<dim3(3584), dim3(256), 0, stream>>>(Wphi, Wpsi, Wnode, Wrel, W3t, Wrelt);
  k_gemm<<<dim3(256), dim3(256), 0, stream>>>(
      x, feat, W3t, Wrelt, bphi, bpsi, bnode, brel, pairs, Yh, out);
  k_epilogue<<<dim3(1032), dim3(256), 0, stream>>>(Yh, pairs, out);
}

// Round 10
// 42.817 us; speedup vs baseline: 2.5483x; 1.2955x over previous
//
#include <hip/hip_runtime.h>
#include <hip/hip_bf16.h>

// B=8, N=64, P=128, DNODE=2048, DEDGE=1024, DEMB=512, E=32768
// lookup(b,i,j)=b*4096+i*64+j (canonical meshgrid); only 2048 of 32768 edge
// rows used; (e1+e2)*0.5 folds into the gathered GEMM input (linearity).
// Structure = R3 (best: 41.9us) + balanced 256-block GEMM grid + f16-only Yh.
// Lessons burned in: (R4/R6/R7) cross-XCD sw barriers cost 30+us -> kernel
// boundaries; (R8) B-side fused staging = scalar VMEM scatter; (R9) A-side
// fp32 fusion re-reads panels at 2x bytes per tile -> pre-cvt ONCE in prep.

typedef _Float16 h16;
typedef h16 h16x4 __attribute__((ext_vector_type(4)));
typedef h16 h16x8 __attribute__((ext_vector_type(8)));
typedef float f32x4 __attribute__((ext_vector_type(4)));

// ---------------- ws layout (bytes) ----------------
static const long O_W3T  = 0;         // 1536*2048*2 = 6291456  (phi|psi|node K-major)
static const long O_WREL = 6291456;   // 512*1024*2  = 1048576
static const long O_XH   = 7340032;   // 512*2048*2  = 2097152
static const long O_G    = 9437184;   // 1024*1024*2 = 2097152  (0.5*(f_fwd+f_rev) f16)
static const long O_B3   = 11534336;  // 1536*4
static const long O_YH   = 11540480;  // 512*1536*2  = 1572864  (phi|psi|node f16)

__global__ __launch_bounds__(256) void k_prep(
    const float* __restrict__ Wphi, const float* __restrict__ Wpsi,
    const float* __restrict__ Wnode, const float* __restrict__ Wrel,
    const float* __restrict__ x, const float* __restrict__ bphi,
    const float* __restrict__ bpsi, const float* __restrict__ bnode,
    const float* __restrict__ feat, const int* __restrict__ pairs,
    h16* __restrict__ W3t, h16* __restrict__ Wrelt, h16* __restrict__ xh,
    float* __restrict__ b3, h16* __restrict__ G) {
  __shared__ float t[32][33];
  int bid = blockIdx.x, tid = threadIdx.x;
  if (bid < 3584) {
    // weight transpose+cvt, 32x32 tile: float4 loads, h16x4 stores
    const float* src; h16* dst; int K, tk, tn;
    if (bid < 3072) {
      int mat = bid >> 10, rem = bid & 1023;
      tk = rem >> 4; tn = rem & 15;
      src = mat == 0 ? Wphi : (mat == 1 ? Wpsi : Wnode);
      K = 2048; dst = W3t + (long)mat * 512 * 2048;
    } else {
      int rem = bid - 3072;
      tk = rem >> 4; tn = rem & 15;
      src = Wrel; K = 1024; dst = Wrelt;
    }
    {
      int row = tid >> 3, c4 = (tid & 7) * 4;   // 32 rows x 8 float4
      float4 v = *(const float4*)(src + (long)(tk*32 + row)*512 + tn*32 + c4);
      t[row][c4+0] = v.x; t[row][c4+1] = v.y; t[row][c4+2] = v.z; t[row][c4+3] = v.w;
    }
    __syncthreads();
    {
      int n = tid >> 3, k4 = (tid & 7) * 4;     // 32 n-rows x 8 h16x4
      h16x4 o = { (h16)t[k4+0][n], (h16)t[k4+1][n], (h16)t[k4+2][n], (h16)t[k4+3][n] };
      *(h16x4*)(dst + (long)(tn*32 + n)*K + tk*32 + k4) = o;
    }
  } else if (bid < 4102) {
    int b2 = bid - 3584;
    if (b2 < 512) {
      int idx = (b2*256 + tid) * 8;
      const float4* xv = (const float4*)(x + idx);
      float4 v0 = xv[0], v1 = xv[1];
      h16x8 o;
      o[0]=(h16)v0.x; o[1]=(h16)v0.y; o[2]=(h16)v0.z; o[3]=(h16)v0.w;
      o[4]=(h16)v1.x; o[5]=(h16)v1.y; o[6]=(h16)v1.z; o[7]=(h16)v1.w;
      *(h16x8*)(xh + idx) = o;
    } else {
      int i = (b2 - 512)*256 + tid;
      if (i < 1536) b3[i] = i < 512 ? bphi[i] : (i < 1024 ? bpsi[i-512] : bnode[i-1024]);
    }
  } else {
    int r = bid - 4102;            // r = b*128 + p
    int b = r >> 7;
    int i0 = pairs[r*2], i1 = pairs[r*2+1];
    const float4* f0 = (const float4*)(feat + (long)((b*64 + i0)*64 + i1) * 1024);
    const float4* f1 = (const float4*)(feat + (long)((b*64 + i1)*64 + i0) * 1024);
    float4 a = f0[tid], c = f1[tid];
    h16x4 o;
    o[0]=(h16)(0.5f*(a.x+c.x)); o[1]=(h16)(0.5f*(a.y+c.y));
    o[2]=(h16)(0.5f*(a.z+c.z)); o[3]=(h16)(0.5f*(a.w+c.w));
    *(h16x4*)(G + (long)r*1024 + tid*4) = o;
  }
}

__device__ __forceinline__ void mfma_compute(
    const h16 (*__restrict__ As)[72], const h16 (*__restrict__ Bs)[72],
    int wm, int wn, int fr, int kg, f32x4 acc[2][2]) {
#pragma unroll
  for (int kc = 0; kc < 2; ++kc) {
    int kb = kc*32 + kg;
    h16x8 fa0 = *(const h16x8*)&As[wm*32 + fr][kb];
    h16x8 fa1 = *(const h16x8*)&As[wm*32 + 16 + fr][kb];
    h16x8 fb0 = *(const h16x8*)&Bs[wn*32 + fr][kb];
    h16x8 fb1 = *(const h16x8*)&Bs[wn*32 + 16 + fr][kb];
    acc[0][0] = __builtin_amdgcn_mfma_f32_16x16x32_f16(fa0, fb0, acc[0][0], 0,0,0);
    acc[0][1] = __builtin_amdgcn_mfma_f32_16x16x32_f16(fa0, fb1, acc[0][1], 0,0,0);
    acc[1][0] = __builtin_amdgcn_mfma_f32_16x16x32_f16(fa1, fb0, acc[1][0], 0,0,0);
    acc[1][1] = __builtin_amdgcn_mfma_f32_16x16x32_f16(fa1, fb1, acc[1][1], 0,0,0);
  }
}

// Double-buffered reg-staged pipeline, ONE barrier per K-step (verified R3).
#define GEMM_PIPELINE(Agp, Bgp, K)                                        \
  {                                                                       \
    h16x8 ra0 = *(const h16x8*)(Agp);                                     \
    h16x8 ra1 = *(const h16x8*)(Agp + 8);                                 \
    h16x8 rb0 = *(const h16x8*)(Bgp);                                     \
    h16x8 rb1 = *(const h16x8*)(Bgp + 8);                                 \
    *(h16x8*)&As[0][srow][skp]   = ra0;                                   \
    *(h16x8*)&As[0][srow][skp+8] = ra1;                                   \
    *(h16x8*)&Bs[0][srow][skp]   = rb0;                                   \
    *(h16x8*)&Bs[0][srow][skp+8] = rb1;                                   \
    __syncthreads();                                                      \
    int cur = 0;                                                          \
    for (int k0 = 64; k0 < (K); k0 += 64) {                               \
      ra0 = *(const h16x8*)(Agp + k0);                                    \
      ra1 = *(const h16x8*)(Agp + k0 + 8);                                \
      rb0 = *(const h16x8*)(Bgp + k0);                                    \
      rb1 = *(const h16x8*)(Bgp + k0 + 8);                                \
      mfma_compute(As[cur], Bs[cur], wm, wn, fr, kg, acc);                \
      int nxt = cur ^ 1;                                                  \
      *(h16x8*)&As[nxt][srow][skp]   = ra0;                               \
      *(h16x8*)&As[nxt][srow][skp+8] = ra1;                               \
      *(h16x8*)&Bs[nxt][srow][skp]   = rb0;                               \
      *(h16x8*)&Bs[nxt][srow][skp+8] = rb1;                               \
      __syncthreads();                                                    \
      cur = nxt;                                                          \
    }                                                                     \
    mfma_compute(As[cur], Bs[cur], wm, wn, fr, kg, acc);                  \
  }

// 256 blocks, balanced: bid<192 -> one main tile (32 K-steps);
// bid in 192..255 -> TWO edge tiles (2 x 16 K-steps). All CUs finish together.
__global__ __launch_bounds__(256) void k_gemm(
    const h16* __restrict__ xh, const h16* __restrict__ W3t,
    const float* __restrict__ b3, h16* __restrict__ Yh,
    const h16* __restrict__ G, const h16* __restrict__ Wrelt,
    const float* __restrict__ brel, float* __restrict__ out) {
  __shared__ __align__(16) h16 As[2][64][72];
  __shared__ __align__(16) h16 Bs[2][64][72];
  int bid = blockIdx.x, tid = threadIdx.x;
  int lane = tid & 63, wave = tid >> 6;
  int wm = wave >> 1, wn = wave & 1;
  int srow = tid >> 2, skp = (tid & 3) * 16;
  int fr = lane & 15, kg = (lane >> 4) * 8;

  int isEdge = bid >= 192;
  int ntile = isEdge ? 2 : 1;
#pragma unroll 1
  for (int ti = 0; ti < ntile; ++ti) {
    if (ti) __syncthreads();
    const h16 *A, *Bt; int K, tileM, tileN;
    if (!isEdge) {               // Yh(512x1536) = xh @ W3t^T + b3
      A = xh; Bt = W3t; K = 2048;
      tileM = (bid / 24) * 64; tileN = (bid % 24) * 64;
    } else {                     // edge(1024x512) = G @ Wrelt^T + brel
      int e = (bid - 192) * 2 + ti;           // 128 tiles
      A = G; Bt = Wrelt; K = 1024;
      tileM = (e >> 3) * 64; tileN = (e & 7) * 64;
    }
    const h16* Agp = A + (long)(tileM + srow) * K + skp;
    const h16* Bgp = Bt + (long)(tileN + srow) * K + skp;
    f32x4 acc[2][2] = {};
    GEMM_PIPELINE(Agp, Bgp, K);
    int r0 = 4 * (lane >> 4), c0 = lane & 15;
#pragma unroll
    for (int m = 0; m < 2; ++m)
#pragma unroll
      for (int n = 0; n < 2; ++n) {
        int row = tileM + wm*32 + m*16 + r0;
        int col = tileN + wn*32 + n*16 + c0;
        if (!isEdge) {
          float bb = b3[col];
#pragma unroll
          for (int r = 0; r < 4; ++r)
            Yh[(long)(row + r) * 1536 + col] = (h16)(acc[m][n][r] + bb);
        } else {
          float bb = brel[col];
#pragma unroll
          for (int r = 0; r < 4; ++r)
            out[32768 + 512 + (long)(row + r) * 1024 + col] = acc[m][n][r] + bb;
        }
      }
  }
}

// blocks 0..7: scores = sigmoid(phi_h @ psi_h^T) per batch (K=512);
// blocks 8..1031: first half from Yh node cols.
__global__ __launch_bounds__(256) void k_epilogue(
    const h16* __restrict__ Yh, const int* __restrict__ pairs,
    float* __restrict__ out) {
  __shared__ __align__(16) h16 As[2][64][72];
  __shared__ __align__(16) h16 Bs[2][64][72];
  int bid = blockIdx.x, tid = threadIdx.x;
  if (bid < 8) {
    int lane = tid & 63, wave = tid >> 6;
    int wm = wave >> 1, wn = wave & 1;
    int srow = tid >> 2, skp = (tid & 3) * 16;
    int fr = lane & 15, kg = (lane >> 4) * 8;
    const h16* Ab = Yh + (long)bid * 64 * 1536;
    const h16* Agp = Ab + (long)srow * 1536 + skp;         // phi rows
    const h16* Bgp = Ab + (long)srow * 1536 + 512 + skp;   // psi rows
    f32x4 acc[2][2] = {};
    GEMM_PIPELINE(Agp, Bgp, 512);
    int r0 = 4 * (lane >> 4), c0 = lane & 15;
    float* ob = out + (long)bid * 4096;
#pragma unroll
    for (int m = 0; m < 2; ++m)
#pragma unroll
      for (int n = 0; n < 2; ++n) {
        int row = wm*32 + m*16 + r0;
        int col = wn*32 + n*16 + c0;
#pragma unroll
        for (int r = 0; r < 4; ++r) {
          float s = acc[m][n][r];
          ob[(long)(row + r) * 64 + col] = 1.f / (1.f + expf(-s));
        }
      }
  } else {
    int r = bid - 8;
    int b = r >> 7;
    int i0 = pairs[r*2], i1 = pairs[r*2+1];
    const h16* n0 = Yh + (long)(b*64 + i0)*1536 + 1024;
    const h16* n1 = Yh + (long)(b*64 + i1)*1536 + 1024;
    float* o = out + 32768 + (long)r*1024;
    for (int c = tid; c < 512; c += 256)
      o[c] = 0.5f*((float)n0[c] + (float)n1[c]);
  }
}

extern "C" void kernel_launch(void* const* d_in, const int* in_sizes, int n_in,
                              void* d_out, int out_size, void* d_ws, size_t ws_size,
                              hipStream_t stream) {
  const float* x     = (const float*)d_in[0];
  const float* feat  = (const float*)d_in[1];
  const float* Wphi  = (const float*)d_in[2];
  const float* bphi  = (const float*)d_in[3];
  const float* Wpsi  = (const float*)d_in[4];
  const float* bpsi  = (const float*)d_in[5];
  const float* Wnode = (const float*)d_in[6];
  const float* bnode = (const float*)d_in[7];
  const float* Wrel  = (const float*)d_in[8];
  const float* brel  = (const float*)d_in[9];
  const int*   pairs = (const int*)d_in[10];
  float* out = (float*)d_out;
  char* ws = (char*)d_ws;

  h16*   W3t   = (h16*)(ws + O_W3T);
  h16*   Wrelt = (h16*)(ws + O_WREL);
  h16*   xh    = (h16*)(ws + O_XH);
  h16*   G     = (h16*)(ws + O_G);
  float* b3    = (float*)(ws + O_B3);
  h16*   Yh    = (h16*)(ws + O_YH);

  k_prep<<<dim3(5126), dim3(256), 0, stream>>>(
      Wphi, Wpsi, Wnode, Wrel, x, bphi, bpsi, bnode, feat, pairs,
      W3t, Wrelt, xh, b3, G);
  k_gemm<<<dim3(256), dim3(256), 0, stream>>>(
      xh, W3t, b3, Yh, G, Wrelt, brel, out);
  k_epilogue<<<dim3(1032), dim3(256), 0, stream>>>(Yh, pairs, out);
}

// Round 11
// 38.184 us; speedup vs baseline: 2.8575x; 1.1213x over previous
//
#include <hip/hip_runtime.h>
#include <hip/hip_bf16.h>

// B=8, N=64, P=128, DNODE=2048, DEDGE=1024, DEMB=512, E=32768
// lookup(b,i,j)=b*4096+i*64+j (canonical meshgrid); only 2048 of 32768 edge
// rows used; (e1+e2)*0.5 folds into the gathered GEMM input (linearity).
// Budget (R6-derived): prep+epilogue+gaps ~8us, k_gemm ~30us at ~7% MFMA eff
// -> latency-bound at 1 wave/SIMD. This round: k_gemm goes 512 threads /
// 8 waves (2 waves/SIMD TLP), each wave a 32x16 sub-tile. Everything else
// (prep, epilogue, pipeline order, numerics) identical to R10.

typedef _Float16 h16;
typedef h16 h16x4 __attribute__((ext_vector_type(4)));
typedef h16 h16x8 __attribute__((ext_vector_type(8)));
typedef float f32x4 __attribute__((ext_vector_type(4)));

// ---------------- ws layout (bytes) ----------------
static const long O_W3T  = 0;         // 1536*2048*2 = 6291456  (phi|psi|node K-major)
static const long O_WREL = 6291456;   // 512*1024*2  = 1048576
static const long O_XH   = 7340032;   // 512*2048*2  = 2097152
static const long O_G    = 9437184;   // 1024*1024*2 = 2097152  (0.5*(f_fwd+f_rev) f16)
static const long O_B3   = 11534336;  // 1536*4
static const long O_YH   = 11540480;  // 512*1536*2  = 1572864  (phi|psi|node f16)

__global__ __launch_bounds__(256) void k_prep(
    const float* __restrict__ Wphi, const float* __restrict__ Wpsi,
    const float* __restrict__ Wnode, const float* __restrict__ Wrel,
    const float* __restrict__ x, const float* __restrict__ bphi,
    const float* __restrict__ bpsi, const float* __restrict__ bnode,
    const float* __restrict__ feat, const int* __restrict__ pairs,
    h16* __restrict__ W3t, h16* __restrict__ Wrelt, h16* __restrict__ xh,
    float* __restrict__ b3, h16* __restrict__ G) {
  __shared__ float t[32][33];
  int bid = blockIdx.x, tid = threadIdx.x;
  if (bid < 3584) {
    // weight transpose+cvt, 32x32 tile: float4 loads, h16x4 stores
    const float* src; h16* dst; int K, tk, tn;
    if (bid < 3072) {
      int mat = bid >> 10, rem = bid & 1023;
      tk = rem >> 4; tn = rem & 15;
      src = mat == 0 ? Wphi : (mat == 1 ? Wpsi : Wnode);
      K = 2048; dst = W3t + (long)mat * 512 * 2048;
    } else {
      int rem = bid - 3072;
      tk = rem >> 4; tn = rem & 15;
      src = Wrel; K = 1024; dst = Wrelt;
    }
    {
      int row = tid >> 3, c4 = (tid & 7) * 4;   // 32 rows x 8 float4
      float4 v = *(const float4*)(src + (long)(tk*32 + row)*512 + tn*32 + c4);
      t[row][c4+0] = v.x; t[row][c4+1] = v.y; t[row][c4+2] = v.z; t[row][c4+3] = v.w;
    }
    __syncthreads();
    {
      int n = tid >> 3, k4 = (tid & 7) * 4;     // 32 n-rows x 8 h16x4
      h16x4 o = { (h16)t[k4+0][n], (h16)t[k4+1][n], (h16)t[k4+2][n], (h16)t[k4+3][n] };
      *(h16x4*)(dst + (long)(tn*32 + n)*K + tk*32 + k4) = o;
    }
  } else if (bid < 4102) {
    int b2 = bid - 3584;
    if (b2 < 512) {
      int idx = (b2*256 + tid) * 8;
      const float4* xv = (const float4*)(x + idx);
      float4 v0 = xv[0], v1 = xv[1];
      h16x8 o;
      o[0]=(h16)v0.x; o[1]=(h16)v0.y; o[2]=(h16)v0.z; o[3]=(h16)v0.w;
      o[4]=(h16)v1.x; o[5]=(h16)v1.y; o[6]=(h16)v1.z; o[7]=(h16)v1.w;
      *(h16x8*)(xh + idx) = o;
    } else {
      int i = (b2 - 512)*256 + tid;
      if (i < 1536) b3[i] = i < 512 ? bphi[i] : (i < 1024 ? bpsi[i-512] : bnode[i-1024]);
    }
  } else {
    int r = bid - 4102;            // r = b*128 + p
    int b = r >> 7;
    int i0 = pairs[r*2], i1 = pairs[r*2+1];
    const float4* f0 = (const float4*)(feat + (long)((b*64 + i0)*64 + i1) * 1024);
    const float4* f1 = (const float4*)(feat + (long)((b*64 + i1)*64 + i0) * 1024);
    float4 a = f0[tid], c = f1[tid];
    h16x4 o;
    o[0]=(h16)(0.5f*(a.x+c.x)); o[1]=(h16)(0.5f*(a.y+c.y));
    o[2]=(h16)(0.5f*(a.z+c.z)); o[3]=(h16)(0.5f*(a.w+c.w));
    *(h16x4*)(G + (long)r*1024 + tid*4) = o;
  }
}

// 4-wave 32x32 compute (verified) — used by the epilogue scores GEMM.
__device__ __forceinline__ void mfma_compute(
    const h16 (*__restrict__ As)[72], const h16 (*__restrict__ Bs)[72],
    int wm, int wn, int fr, int kg, f32x4 acc[2][2]) {
#pragma unroll
  for (int kc = 0; kc < 2; ++kc) {
    int kb = kc*32 + kg;
    h16x8 fa0 = *(const h16x8*)&As[wm*32 + fr][kb];
    h16x8 fa1 = *(const h16x8*)&As[wm*32 + 16 + fr][kb];
    h16x8 fb0 = *(const h16x8*)&Bs[wn*32 + fr][kb];
    h16x8 fb1 = *(const h16x8*)&Bs[wn*32 + 16 + fr][kb];
    acc[0][0] = __builtin_amdgcn_mfma_f32_16x16x32_f16(fa0, fb0, acc[0][0], 0,0,0);
    acc[0][1] = __builtin_amdgcn_mfma_f32_16x16x32_f16(fa0, fb1, acc[0][1], 0,0,0);
    acc[1][0] = __builtin_amdgcn_mfma_f32_16x16x32_f16(fa1, fb0, acc[1][0], 0,0,0);
    acc[1][1] = __builtin_amdgcn_mfma_f32_16x16x32_f16(fa1, fb1, acc[1][1], 0,0,0);
  }
}

// 8-wave 32x16 compute — k_gemm (512 threads). 3 ds_reads / 2 MFMA per kc.
__device__ __forceinline__ void mfma_compute8(
    const h16 (*__restrict__ As)[72], const h16 (*__restrict__ Bs)[72],
    int wm, int wn, int fr, int kg, f32x4 acc[2]) {
#pragma unroll
  for (int kc = 0; kc < 2; ++kc) {
    int kb = kc*32 + kg;
    h16x8 fa0 = *(const h16x8*)&As[wm*32 + fr][kb];
    h16x8 fa1 = *(const h16x8*)&As[wm*32 + 16 + fr][kb];
    h16x8 fb  = *(const h16x8*)&Bs[wn*16 + fr][kb];
    acc[0] = __builtin_amdgcn_mfma_f32_16x16x32_f16(fa0, fb, acc[0], 0,0,0);
    acc[1] = __builtin_amdgcn_mfma_f32_16x16x32_f16(fa1, fb, acc[1], 0,0,0);
  }
}

// 256 blocks x 512 threads (8 waves, 2/SIMD). bid<192: one main tile (32 steps);
// bid 192..255: TWO edge tiles (2x16 steps). Dbuf reg-staged, 1 barrier/step.
__global__ __launch_bounds__(512) void k_gemm(
    const h16* __restrict__ xh, const h16* __restrict__ W3t,
    const float* __restrict__ b3, h16* __restrict__ Yh,
    const h16* __restrict__ G, const h16* __restrict__ Wrelt,
    const float* __restrict__ brel, float* __restrict__ out) {
  __shared__ __align__(16) h16 As[2][64][72];
  __shared__ __align__(16) h16 Bs[2][64][72];
  int bid = blockIdx.x, tid = threadIdx.x;
  int lane = tid & 63, wave = tid >> 6;   // 0..7
  int wm = wave >> 2, wn = wave & 3;      // 2 x 4 -> 32 rows x 16 cols per wave
  int srow = tid >> 3, skp = (tid & 7) * 8;  // staging: 64 rows x 8 k-segments
  int fr = lane & 15, kg = (lane >> 4) * 8;

  int isEdge = bid >= 192;
  int ntile = isEdge ? 2 : 1;
#pragma unroll 1
  for (int ti = 0; ti < ntile; ++ti) {
    if (ti) __syncthreads();
    const h16 *A, *Bt; int K, tileM, tileN;
    if (!isEdge) {               // Yh(512x1536) = xh @ W3t^T + b3
      A = xh; Bt = W3t; K = 2048;
      tileM = (bid / 24) * 64; tileN = (bid % 24) * 64;
    } else {                     // edge(1024x512) = G @ Wrelt^T + brel
      int e = (bid - 192) * 2 + ti;           // 128 tiles
      A = G; Bt = Wrelt; K = 1024;
      tileM = (e >> 3) * 64; tileN = (e & 7) * 64;
    }
    const h16* Agp = A + (long)(tileM + srow) * K + skp;
    const h16* Bgp = Bt + (long)(tileN + srow) * K + skp;
    f32x4 acc[2] = {};
    h16x8 ra = *(const h16x8*)(Agp);
    h16x8 rb = *(const h16x8*)(Bgp);
    *(h16x8*)&As[0][srow][skp] = ra;
    *(h16x8*)&Bs[0][srow][skp] = rb;
    __syncthreads();
    int cur = 0;
#pragma unroll 1
    for (int k0 = 64; k0 < K; k0 += 64) {
      ra = *(const h16x8*)(Agp + k0);
      rb = *(const h16x8*)(Bgp + k0);
      mfma_compute8(As[cur], Bs[cur], wm, wn, fr, kg, acc);
      int nxt = cur ^ 1;
      *(h16x8*)&As[nxt][srow][skp] = ra;
      *(h16x8*)&Bs[nxt][srow][skp] = rb;
      __syncthreads();
      cur = nxt;
    }
    mfma_compute8(As[cur], Bs[cur], wm, wn, fr, kg, acc);

    int r0 = 4 * (lane >> 4);
#pragma unroll
    for (int m = 0; m < 2; ++m) {
      int row = tileM + wm*32 + m*16 + r0;
      int col = tileN + wn*16 + fr;
      if (!isEdge) {
        float bb = b3[col];
#pragma unroll
        for (int r = 0; r < 4; ++r)
          Yh[(long)(row + r) * 1536 + col] = (h16)(acc[m][r] + bb);
      } else {
        float bb = brel[col];
#pragma unroll
        for (int r = 0; r < 4; ++r)
          out[32768 + 512 + (long)(row + r) * 1024 + col] = acc[m][r] + bb;
      }
    }
  }
}

// Double-buffered reg-staged pipeline (verified R3/R10) — epilogue scores only.
#define GEMM_PIPELINE(Agp, Bgp, K)                                        \
  {                                                                       \
    h16x8 ra0 = *(const h16x8*)(Agp);                                     \
    h16x8 ra1 = *(const h16x8*)(Agp + 8);                                 \
    h16x8 rb0 = *(const h16x8*)(Bgp);                                     \
    h16x8 rb1 = *(const h16x8*)(Bgp + 8);                                 \
    *(h16x8*)&As[0][srow][skp]   = ra0;                                   \
    *(h16x8*)&As[0][srow][skp+8] = ra1;                                   \
    *(h16x8*)&Bs[0][srow][skp]   = rb0;                                   \
    *(h16x8*)&Bs[0][srow][skp+8] = rb1;                                   \
    __syncthreads();                                                      \
    int cur = 0;                                                          \
    for (int k0 = 64; k0 < (K); k0 += 64) {                               \
      ra0 = *(const h16x8*)(Agp + k0);                                    \
      ra1 = *(const h16x8*)(Agp + k0 + 8);                                \
      rb0 = *(const h16x8*)(Bgp + k0);                                    \
      rb1 = *(const h16x8*)(Bgp + k0 + 8);                                \
      mfma_compute(As[cur], Bs[cur], wm, wn, fr, kg, acc);                \
      int nxt = cur ^ 1;                                                  \
      *(h16x8*)&As[nxt][srow][skp]   = ra0;                               \
      *(h16x8*)&As[nxt][srow][skp+8] = ra1;                               \
      *(h16x8*)&Bs[nxt][srow][skp]   = rb0;                               \
      *(h16x8*)&Bs[nxt][srow][skp+8] = rb1;                               \
      __syncthreads();                                                    \
      cur = nxt;                                                          \
    }                                                                     \
    mfma_compute(As[cur], Bs[cur], wm, wn, fr, kg, acc);                  \
  }

// blocks 0..7: scores = sigmoid(phi_h @ psi_h^T) per batch (K=512);
// blocks 8..1031: first half from Yh node cols.
__global__ __launch_bounds__(256) void k_epilogue(
    const h16* __restrict__ Yh, const int* __restrict__ pairs,
    float* __restrict__ out) {
  __shared__ __align__(16) h16 As[2][64][72];
  __shared__ __align__(16) h16 Bs[2][64][72];
  int bid = blockIdx.x, tid = threadIdx.x;
  if (bid < 8) {
    int lane = tid & 63, wave = tid >> 6;
    int wm = wave >> 1, wn = wave & 1;
    int srow = tid >> 2, skp = (tid & 3) * 16;
    int fr = lane & 15, kg = (lane >> 4) * 8;
    const h16* Ab = Yh + (long)bid * 64 * 1536;
    const h16* Agp = Ab + (long)srow * 1536 + skp;         // phi rows
    const h16* Bgp = Ab + (long)srow * 1536 + 512 + skp;   // psi rows
    f32x4 acc[2][2] = {};
    GEMM_PIPELINE(Agp, Bgp, 512);
    int r0 = 4 * (lane >> 4), c0 = lane & 15;
    float* ob = out + (long)bid * 4096;
#pragma unroll
    for (int m = 0; m < 2; ++m)
#pragma unroll
      for (int n = 0; n < 2; ++n) {
        int row = wm*32 + m*16 + r0;
        int col = wn*32 + n*16 + c0;
#pragma unroll
        for (int r = 0; r < 4; ++r) {
          float s = acc[m][n][r];
          ob[(long)(row + r) * 64 + col] = 1.f / (1.f + expf(-s));
        }
      }
  } else {
    int r = bid - 8;
    int b = r >> 7;
    int i0 = pairs[r*2], i1 = pairs[r*2+1];
    const h16* n0 = Yh + (long)(b*64 + i0)*1536 + 1024;
    const h16* n1 = Yh + (long)(b*64 + i1)*1536 + 1024;
    float* o = out + 32768 + (long)r*1024;
    for (int c = tid; c < 512; c += 256)
      o[c] = 0.5f*((float)n0[c] + (float)n1[c]);
  }
}

extern "C" void kernel_launch(void* const* d_in, const int* in_sizes, int n_in,
                              void* d_out, int out_size, void* d_ws, size_t ws_size,
                              hipStream_t stream) {
  const float* x     = (const float*)d_in[0];
  const float* feat  = (const float*)d_in[1];
  const float* Wphi  = (const float*)d_in[2];
  const float* bphi  = (const float*)d_in[3];
  const float* Wpsi  = (const float*)d_in[4];
  const float* bpsi  = (const float*)d_in[5];
  const float* Wnode = (const float*)d_in[6];
  const float* bnode = (const float*)d_in[7];
  const float* Wrel  = (const float*)d_in[8];
  const float* brel  = (const float*)d_in[9];
  const int*   pairs = (const int*)d_in[10];
  float* out = (float*)d_out;
  char* ws = (char*)d_ws;

  h16*   W3t   = (h16*)(ws + O_W3T);
  h16*   Wrelt = (h16*)(ws + O_WREL);
  h16*   xh    = (h16*)(ws + O_XH);
  h16*   G     = (h16*)(ws + O_G);
  float* b3    = (float*)(ws + O_B3);
  h16*   Yh    = (h16*)(ws + O_YH);

  k_prep<<<dim3(5126), dim3(256), 0, stream>>>(
      Wphi, Wpsi, Wnode, Wrel, x, bphi, bpsi, bnode, feat, pairs,
      W3t, Wrelt, xh, b3, G);
  k_gemm<<<dim3(256), dim3(512), 0, stream>>>(
      xh, W3t, b3, Yh, G, Wrelt, brel, out);
  k_epilogue<<<dim3(1032), dim3(256), 0, stream>>>(Yh, pairs, out);
}

// Round 12
// 36.608 us; speedup vs baseline: 2.9805x; 1.0431x over previous
//
#include <hip/hip_runtime.h>
#include <hip/hip_bf16.h>

// B=8, N=64, P=128, DNODE=2048, DEDGE=1024, DEMB=512, E=32768
// lookup(b,i,j)=b*4096+i*64+j (canonical meshgrid); only 2048 of 32768 edge
// rows used; (e1+e2)*0.5 folds into the gathered GEMM input (linearity).
// R11 lesson: __syncthreads() drains vmcnt(0) -> prefetch loads serialize at
// every K-step barrier. This round k_gemm uses {s_waitcnt lgkmcnt(0); s_barrier}
// (publishes LDS writes, keeps global loads in flight) + depth-2 reg prefetch
// (load k+2 issued at step k, ~2 steps of latency budget). 8 waves/block.

typedef _Float16 h16;
typedef h16 h16x4 __attribute__((ext_vector_type(4)));
typedef h16 h16x8 __attribute__((ext_vector_type(8)));
typedef float f32x4 __attribute__((ext_vector_type(4)));

// ---------------- ws layout (bytes) ----------------
static const long O_W3T  = 0;         // 1536*2048*2 = 6291456  (phi|psi|node K-major)
static const long O_WREL = 6291456;   // 512*1024*2  = 1048576
static const long O_XH   = 7340032;   // 512*2048*2  = 2097152
static const long O_G    = 9437184;   // 1024*1024*2 = 2097152  (0.5*(f_fwd+f_rev) f16)
static const long O_B3   = 11534336;  // 1536*4
static const long O_YH   = 11540480;  // 512*1536*2  = 1572864  (phi|psi|node f16)

__global__ __launch_bounds__(256) void k_prep(
    const float* __restrict__ Wphi, const float* __restrict__ Wpsi,
    const float* __restrict__ Wnode, const float* __restrict__ Wrel,
    const float* __restrict__ x, const float* __restrict__ bphi,
    const float* __restrict__ bpsi, const float* __restrict__ bnode,
    const float* __restrict__ feat, const int* __restrict__ pairs,
    h16* __restrict__ W3t, h16* __restrict__ Wrelt, h16* __restrict__ xh,
    float* __restrict__ b3, h16* __restrict__ G) {
  __shared__ float t[32][33];
  int bid = blockIdx.x, tid = threadIdx.x;
  if (bid < 3584) {
    // weight transpose+cvt, 32x32 tile: float4 loads, h16x4 stores
    const float* src; h16* dst; int K, tk, tn;
    if (bid < 3072) {
      int mat = bid >> 10, rem = bid & 1023;
      tk = rem >> 4; tn = rem & 15;
      src = mat == 0 ? Wphi : (mat == 1 ? Wpsi : Wnode);
      K = 2048; dst = W3t + (long)mat * 512 * 2048;
    } else {
      int rem = bid - 3072;
      tk = rem >> 4; tn = rem & 15;
      src = Wrel; K = 1024; dst = Wrelt;
    }
    {
      int row = tid >> 3, c4 = (tid & 7) * 4;   // 32 rows x 8 float4
      float4 v = *(const float4*)(src + (long)(tk*32 + row)*512 + tn*32 + c4);
      t[row][c4+0] = v.x; t[row][c4+1] = v.y; t[row][c4+2] = v.z; t[row][c4+3] = v.w;
    }
    __syncthreads();
    {
      int n = tid >> 3, k4 = (tid & 7) * 4;     // 32 n-rows x 8 h16x4
      h16x4 o = { (h16)t[k4+0][n], (h16)t[k4+1][n], (h16)t[k4+2][n], (h16)t[k4+3][n] };
      *(h16x4*)(dst + (long)(tn*32 + n)*K + tk*32 + k4) = o;
    }
  } else if (bid < 4102) {
    int b2 = bid - 3584;
    if (b2 < 512) {
      int idx = (b2*256 + tid) * 8;
      const float4* xv = (const float4*)(x + idx);
      float4 v0 = xv[0], v1 = xv[1];
      h16x8 o;
      o[0]=(h16)v0.x; o[1]=(h16)v0.y; o[2]=(h16)v0.z; o[3]=(h16)v0.w;
      o[4]=(h16)v1.x; o[5]=(h16)v1.y; o[6]=(h16)v1.z; o[7]=(h16)v1.w;
      *(h16x8*)(xh + idx) = o;
    } else {
      int i = (b2 - 512)*256 + tid;
      if (i < 1536) b3[i] = i < 512 ? bphi[i] : (i < 1024 ? bpsi[i-512] : bnode[i-1024]);
    }
  } else {
    int r = bid - 4102;            // r = b*128 + p
    int b = r >> 7;
    int i0 = pairs[r*2], i1 = pairs[r*2+1];
    const float4* f0 = (const float4*)(feat + (long)((b*64 + i0)*64 + i1) * 1024);
    const float4* f1 = (const float4*)(feat + (long)((b*64 + i1)*64 + i0) * 1024);
    float4 a = f0[tid], c = f1[tid];
    h16x4 o;
    o[0]=(h16)(0.5f*(a.x+c.x)); o[1]=(h16)(0.5f*(a.y+c.y));
    o[2]=(h16)(0.5f*(a.z+c.z)); o[3]=(h16)(0.5f*(a.w+c.w));
    *(h16x4*)(G + (long)r*1024 + tid*4) = o;
  }
}

// 4-wave 32x32 compute (verified) — epilogue scores GEMM.
__device__ __forceinline__ void mfma_compute(
    const h16 (*__restrict__ As)[72], const h16 (*__restrict__ Bs)[72],
    int wm, int wn, int fr, int kg, f32x4 acc[2][2]) {
#pragma unroll
  for (int kc = 0; kc < 2; ++kc) {
    int kb = kc*32 + kg;
    h16x8 fa0 = *(const h16x8*)&As[wm*32 + fr][kb];
    h16x8 fa1 = *(const h16x8*)&As[wm*32 + 16 + fr][kb];
    h16x8 fb0 = *(const h16x8*)&Bs[wn*32 + fr][kb];
    h16x8 fb1 = *(const h16x8*)&Bs[wn*32 + 16 + fr][kb];
    acc[0][0] = __builtin_amdgcn_mfma_f32_16x16x32_f16(fa0, fb0, acc[0][0], 0,0,0);
    acc[0][1] = __builtin_amdgcn_mfma_f32_16x16x32_f16(fa0, fb1, acc[0][1], 0,0,0);
    acc[1][0] = __builtin_amdgcn_mfma_f32_16x16x32_f16(fa1, fb0, acc[1][0], 0,0,0);
    acc[1][1] = __builtin_amdgcn_mfma_f32_16x16x32_f16(fa1, fb1, acc[1][1], 0,0,0);
  }
}

// 8-wave 32x16 compute — k_gemm (512 threads).
__device__ __forceinline__ void mfma_compute8(
    const h16 (*__restrict__ As)[72], const h16 (*__restrict__ Bs)[72],
    int wm, int wn, int fr, int kg, f32x4 acc[2]) {
#pragma unroll
  for (int kc = 0; kc < 2; ++kc) {
    int kb = kc*32 + kg;
    h16x8 fa0 = *(const h16x8*)&As[wm*32 + fr][kb];
    h16x8 fa1 = *(const h16x8*)&As[wm*32 + 16 + fr][kb];
    h16x8 fb  = *(const h16x8*)&Bs[wn*16 + fr][kb];
    acc[0] = __builtin_amdgcn_mfma_f32_16x16x32_f16(fa0, fb, acc[0], 0,0,0);
    acc[1] = __builtin_amdgcn_mfma_f32_16x16x32_f16(fa1, fb, acc[1], 0,0,0);
  }
}

// Publish LDS writes, keep global loads in flight (NO vmcnt drain — T4).
#define BAR_LDS() { asm volatile("s_waitcnt lgkmcnt(0)" ::: "memory"); \
                    __builtin_amdgcn_s_barrier(); }

// 256 blocks x 512 threads (8 waves, 2/SIMD). bid<192: one main tile (32 steps);
// bid 192..255: TWO edge tiles (2x16 steps). Depth-2 prefetch, 1 relaxed
// barrier per K-step.
__global__ __launch_bounds__(512) void k_gemm(
    const h16* __restrict__ xh, const h16* __restrict__ W3t,
    const float* __restrict__ b3, h16* __restrict__ Yh,
    const h16* __restrict__ G, const h16* __restrict__ Wrelt,
    const float* __restrict__ brel, float* __restrict__ out) {
  __shared__ __align__(16) h16 As[2][64][72];
  __shared__ __align__(16) h16 Bs[2][64][72];
  int bid = blockIdx.x, tid = threadIdx.x;
  int lane = tid & 63, wave = tid >> 6;   // 0..7
  int wm = wave >> 2, wn = wave & 3;      // 2 x 4 -> 32 rows x 16 cols per wave
  int srow = tid >> 3, skp = (tid & 7) * 8;  // staging: 64 rows x 8 k-segments
  int fr = lane & 15, kg = (lane >> 4) * 8;

  int isEdge = bid >= 192;
  int ntile = isEdge ? 2 : 1;
#pragma unroll 1
  for (int ti = 0; ti < ntile; ++ti) {
    if (ti) __syncthreads();   // full drain between tiles (once) is fine
    const h16 *A, *Bt; int K, tileM, tileN;
    if (!isEdge) {               // Yh(512x1536) = xh @ W3t^T + b3
      A = xh; Bt = W3t; K = 2048;
      tileM = (bid / 24) * 64; tileN = (bid % 24) * 64;
    } else {                     // edge(1024x512) = G @ Wrelt^T + brel
      int e = (bid - 192) * 2 + ti;           // 128 tiles
      A = G; Bt = Wrelt; K = 1024;
      tileM = (e >> 3) * 64; tileN = (e & 7) * 64;
    }
    const h16* Agp = A + (long)(tileM + srow) * K + skp;
    const h16* Bgp = Bt + (long)(tileN + srow) * K + skp;
    f32x4 acc[2] = {};

    // prologue: step0 regs -> LDS[0]; step1 prefetch stays in flight
    h16x8 ra0 = *(const h16x8*)(Agp);
    h16x8 rb0 = *(const h16x8*)(Bgp);
    *(h16x8*)&As[0][srow][skp] = ra0;
    *(h16x8*)&Bs[0][srow][skp] = rb0;
    h16x8 raN = *(const h16x8*)(Agp + 64);
    h16x8 rbN = *(const h16x8*)(Bgp + 64);
    BAR_LDS();
    int cur = 0;
#pragma unroll 1
    for (int k0 = 128; k0 < K; k0 += 64) {
      h16x8 raF = *(const h16x8*)(Agp + k0);   // prefetch step k0/64 (2 ahead)
      h16x8 rbF = *(const h16x8*)(Bgp + k0);
      *(h16x8*)&As[cur ^ 1][srow][skp] = raN;  // write step (k0-64)/64
      *(h16x8*)&Bs[cur ^ 1][srow][skp] = rbN;  // (auto-counted vmcnt on raN/rbN)
      mfma_compute8(As[cur], Bs[cur], wm, wn, fr, kg, acc);
      BAR_LDS();
      raN = raF; rbN = rbF;
      cur ^= 1;
    }
    // tail: write last prefetched step, compute the final two buffers
    *(h16x8*)&As[cur ^ 1][srow][skp] = raN;
    *(h16x8*)&Bs[cur ^ 1][srow][skp] = rbN;
    mfma_compute8(As[cur], Bs[cur], wm, wn, fr, kg, acc);
    BAR_LDS();
    mfma_compute8(As[cur ^ 1], Bs[cur ^ 1], wm, wn, fr, kg, acc);

    int r0 = 4 * (lane >> 4);
#pragma unroll
    for (int m = 0; m < 2; ++m) {
      int row = tileM + wm*32 + m*16 + r0;
      int col = tileN + wn*16 + fr;
      if (!isEdge) {
        float bb = b3[col];
#pragma unroll
        for (int r = 0; r < 4; ++r)
          Yh[(long)(row + r) * 1536 + col] = (h16)(acc[m][r] + bb);
      } else {
        float bb = brel[col];
#pragma unroll
        for (int r = 0; r < 4; ++r)
          out[32768 + 512 + (long)(row + r) * 1024 + col] = acc[m][r] + bb;
      }
    }
  }
}

// Double-buffered reg-staged pipeline (verified) — epilogue scores only.
#define GEMM_PIPELINE(Agp, Bgp, K)                                        \
  {                                                                       \
    h16x8 ra0 = *(const h16x8*)(Agp);                                     \
    h16x8 ra1 = *(const h16x8*)(Agp + 8);                                 \
    h16x8 rb0 = *(const h16x8*)(Bgp);                                     \
    h16x8 rb1 = *(const h16x8*)(Bgp + 8);                                 \
    *(h16x8*)&As[0][srow][skp]   = ra0;                                   \
    *(h16x8*)&As[0][srow][skp+8] = ra1;                                   \
    *(h16x8*)&Bs[0][srow][skp]   = rb0;                                   \
    *(h16x8*)&Bs[0][srow][skp+8] = rb1;                                   \
    __syncthreads();                                                      \
    int cur = 0;                                                          \
    for (int k0 = 64; k0 < (K); k0 += 64) {                               \
      ra0 = *(const h16x8*)(Agp + k0);                                    \
      ra1 = *(const h16x8*)(Agp + k0 + 8);                                \
      rb0 = *(const h16x8*)(Bgp + k0);                                    \
      rb1 = *(const h16x8*)(Bgp + k0 + 8);                                \
      mfma_compute(As[cur], Bs[cur], wm, wn, fr, kg, acc);                \
      int nxt = cur ^ 1;                                                  \
      *(h16x8*)&As[nxt][srow][skp]   = ra0;                               \
      *(h16x8*)&As[nxt][srow][skp+8] = ra1;                               \
      *(h16x8*)&Bs[nxt][srow][skp]   = rb0;                               \
      *(h16x8*)&Bs[nxt][srow][skp+8] = rb1;                               \
      __syncthreads();                                                    \
      cur = nxt;                                                          \
    }                                                                     \
    mfma_compute(As[cur], Bs[cur], wm, wn, fr, kg, acc);                  \
  }

// blocks 0..7: scores = sigmoid(phi_h @ psi_h^T) per batch (K=512);
// blocks 8..1031: first half from Yh node cols.
__global__ __launch_bounds__(256) void k_epilogue(
    const h16* __restrict__ Yh, const int* __restrict__ pairs,
    float* __restrict__ out) {
  __shared__ __align__(16) h16 As[2][64][72];
  __shared__ __align__(16) h16 Bs[2][64][72];
  int bid = blockIdx.x, tid = threadIdx.x;
  if (bid < 8) {
    int lane = tid & 63, wave = tid >> 6;
    int wm = wave >> 1, wn = wave & 1;
    int srow = tid >> 2, skp = (tid & 3) * 16;
    int fr = lane & 15, kg = (lane >> 4) * 8;
    const h16* Ab = Yh + (long)bid * 64 * 1536;
    const h16* Agp = Ab + (long)srow * 1536 + skp;         // phi rows
    const h16* Bgp = Ab + (long)srow * 1536 + 512 + skp;   // psi rows
    f32x4 acc[2][2] = {};
    GEMM_PIPELINE(Agp, Bgp, 512);
    int r0 = 4 * (lane >> 4), c0 = lane & 15;
    float* ob = out + (long)bid * 4096;
#pragma unroll
    for (int m = 0; m < 2; ++m)
#pragma unroll
      for (int n = 0; n < 2; ++n) {
        int row = wm*32 + m*16 + r0;
        int col = wn*32 + n*16 + c0;
#pragma unroll
        for (int r = 0; r < 4; ++r) {
          float s = acc[m][n][r];
          ob[(long)(row + r) * 64 + col] = 1.f / (1.f + expf(-s));
        }
      }
  } else {
    int r = bid - 8;
    int b = r >> 7;
    int i0 = pairs[r*2], i1 = pairs[r*2+1];
    const h16* n0 = Yh + (long)(b*64 + i0)*1536 + 1024;
    const h16* n1 = Yh + (long)(b*64 + i1)*1536 + 1024;
    float* o = out + 32768 + (long)r*1024;
    for (int c = tid; c < 512; c += 256)
      o[c] = 0.5f*((float)n0[c] + (float)n1[c]);
  }
}

extern "C" void kernel_launch(void* const* d_in, const int* in_sizes, int n_in,
                              void* d_out, int out_size, void* d_ws, size_t ws_size,
                              hipStream_t stream) {
  const float* x     = (const float*)d_in[0];
  const float* feat  = (const float*)d_in[1];
  const float* Wphi  = (const float*)d_in[2];
  const float* bphi  = (const float*)d_in[3];
  const float* Wpsi  = (const float*)d_in[4];
  const float* bpsi  = (const float*)d_in[5];
  const float* Wnode = (const float*)d_in[6];
  const float* bnode = (const float*)d_in[7];
  const float* Wrel  = (const float*)d_in[8];
  const float* brel  = (const float*)d_in[9];
  const int*   pairs = (const int*)d_in[10];
  float* out = (float*)d_out;
  char* ws = (char*)d_ws;

  h16*   W3t   = (h16*)(ws + O_W3T);
  h16*   Wrelt = (h16*)(ws + O_WREL);
  h16*   xh    = (h16*)(ws + O_XH);
  h16*   G     = (h16*)(ws + O_G);
  float* b3    = (float*)(ws + O_B3);
  h16*   Yh    = (h16*)(ws + O_YH);

  k_prep<<<dim3(5126), dim3(256), 0, stream>>>(
      Wphi, Wpsi, Wnode, Wrel, x, bphi, bpsi, bnode, feat, pairs,
      W3t, Wrelt, xh, b3, G);
  k_gemm<<<dim3(256), dim3(512), 0, stream>>>(
      xh, W3t, b3, Yh, G, Wrelt, brel, out);
  k_epilogue<<<dim3(1032), dim3(256), 0, stream>>>(Yh, pairs, out);
}